// Round 5
// baseline (895.727 us; speedup 1.0000x reference)
//
#include <hip/hip_runtime.h>
#include <math.h>

#define HEADS1 4
#define HID 64
#define LSTM_H 32
#define IN_F 128
#define T_STEPS 50
#define NEG_SLOPE 0.2f
#define EPS_A 1e-16f

typedef __attribute__((ext_vector_type(8))) short short8;
typedef __attribute__((ext_vector_type(4))) float floatx4;
typedef __attribute__((ext_vector_type(4))) unsigned uint32x4;

// ---------- helpers ----------
__device__ __forceinline__ float sigf(float x) { return 1.0f / (1.0f + __expf(-x)); }
__device__ __forceinline__ float tanhfast(float x) {
    float e = __expf(2.0f * x);
    return 1.0f - 2.0f / (e + 1.0f);
}
__device__ __forceinline__ unsigned short f2bf(float f) {
    unsigned u = __float_as_uint(f);
    unsigned r = (u + 0x7FFFu + ((u >> 16) & 1u)) >> 16;
    return (unsigned short)r;
}
__device__ __forceinline__ float bf2f(unsigned short s) {
    return __uint_as_float(((unsigned)s) << 16);
}
// HW packed fp32->bf16 (2 values / instruction); no builtin on gfx950, inline asm.
__device__ __forceinline__ unsigned cvt_pk_bf16(float a, float b) {
    unsigned r;
    asm("v_cvt_pk_bf16_f32 %0, %1, %2" : "=v"(r) : "v"(a), "v"(b));
    return r;
}
__device__ __forceinline__ float lo16f(unsigned p) { return __uint_as_float(p << 16); }
__device__ __forceinline__ float hi16f(unsigned p) { return __uint_as_float(p & 0xffff0000u); }

// ---------- GEMM: C[M,NC] = A[M,K] @ B[K,NC]; 64x64 tile, 4x4 micro ----------
template <int K, int NC>
__global__ __launch_bounds__(256) void gemm64(const float* __restrict__ A,
                                              const float* __restrict__ B,
                                              float* __restrict__ C, int M) {
    constexpr int KC = 32;
    __shared__ float As[KC][68];
    __shared__ float Bs[KC][64];
    const int row0 = blockIdx.x * 64;
    const int col0 = blockIdx.y * 64;
    const int tx = threadIdx.x & 15;
    const int ty = threadIdx.x >> 4;
    float acc[4][4] = {{0.f}};

    for (int k0 = 0; k0 < K; k0 += KC) {
        {
            const int kk = threadIdx.x & 31;
            const int rb = threadIdx.x >> 5;
#pragma unroll
            for (int r = 0; r < 8; r++) {
                int row = row0 + rb + r * 8;
                As[kk][rb + r * 8] = (row < M) ? A[(size_t)row * K + k0 + kk] : 0.0f;
            }
            const int c  = threadIdx.x & 63;
            const int kb = threadIdx.x >> 6;
#pragma unroll
            for (int q = 0; q < KC / 4; q++)
                Bs[kb + q * 4][c] = B[(size_t)(k0 + kb + q * 4) * NC + col0 + c];
        }
        __syncthreads();
#pragma unroll
        for (int kk = 0; kk < KC; kk++) {
            float4 a4 = *(const float4*)&As[kk][ty * 4];
            float4 b4 = *(const float4*)&Bs[kk][tx * 4];
            float av[4] = {a4.x, a4.y, a4.z, a4.w};
            float bv[4] = {b4.x, b4.y, b4.z, b4.w};
#pragma unroll
            for (int i = 0; i < 4; i++)
#pragma unroll
                for (int j = 0; j < 4; j++) acc[i][j] += av[i] * bv[j];
        }
        __syncthreads();
    }
#pragma unroll
    for (int i = 0; i < 4; i++) {
        int row = row0 + ty * 4 + i;
        if (row < M) {
            float4 v = make_float4(acc[i][0], acc[i][1], acc[i][2], acc[i][3]);
            *(float4*)&C[(size_t)row * NC + col0 + tx * 4] = v;
        }
    }
}

// ---------- attention scores ----------
__global__ void att_scores(const float* __restrict__ h, const float* __restrict__ att_s,
                           const float* __restrict__ att_d, float* __restrict__ as_,
                           float* __restrict__ ad_, int NH, int Hmask) {
    int i = blockIdx.x * blockDim.x + threadIdx.x;
    if (i >= NH) return;
    int hh = i & Hmask;
    const float* row = h + (size_t)i * HID;
    float s = 0.0f, d = 0.0f;
#pragma unroll 8
    for (int c = 0; c < HID; c++) {
        float v = row[c];
        s += v * att_s[hh * HID + c];
        d += v * att_d[hh * HID + c];
    }
    as_[i] = s;
    ad_[i] = d;
}

// ---------- CSR build ----------
__global__ void count_deg(const int* __restrict__ dsts, int E, int ET, int* __restrict__ cnt) {
    int e = blockIdx.x * blockDim.x + threadIdx.x;
    if (e >= ET) return;
    int d = (e < E) ? dsts[e] : (e - E);
    atomicAdd(&cnt[d], 1);
}

__global__ void scan1(const int* __restrict__ cnt, int* __restrict__ rowp,
                      int* __restrict__ bsum, int N) {
    __shared__ int tmp[256];
    int i = blockIdx.x * 256 + threadIdx.x;
    int v = (i < N) ? cnt[i] : 0;
    tmp[threadIdx.x] = v;
    __syncthreads();
    for (int off = 1; off < 256; off <<= 1) {
        int t = (threadIdx.x >= (unsigned)off) ? tmp[threadIdx.x - off] : 0;
        __syncthreads();
        tmp[threadIdx.x] += t;
        __syncthreads();
    }
    if (i < N) rowp[i] = tmp[threadIdx.x] - v;
    if (threadIdx.x == 255) bsum[blockIdx.x] = tmp[255];
}

__global__ void scan2(int* __restrict__ bsum, int nb) {
    __shared__ int tmp[256];
    int v = (threadIdx.x < (unsigned)nb) ? bsum[threadIdx.x] : 0;
    tmp[threadIdx.x] = v;
    __syncthreads();
    for (int off = 1; off < 256; off <<= 1) {
        int t = (threadIdx.x >= (unsigned)off) ? tmp[threadIdx.x - off] : 0;
        __syncthreads();
        tmp[threadIdx.x] += t;
        __syncthreads();
    }
    if (threadIdx.x < (unsigned)nb) bsum[threadIdx.x] = tmp[threadIdx.x] - v;
}

__global__ void scan3(int* __restrict__ rowp, const int* __restrict__ bsum, int N, int ET) {
    int i = blockIdx.x * 256 + threadIdx.x;
    if (i < N) rowp[i] += bsum[blockIdx.x];
    if (i == 0) rowp[N] = ET;
}

__global__ void scatter_edges(const int* __restrict__ dsts, int E, int ET,
                              const int* __restrict__ rowp, int* __restrict__ cursor,
                              int* __restrict__ eid) {
    int e = blockIdx.x * blockDim.x + threadIdx.x;
    if (e >= ET) return;
    int d = (e < E) ? dsts[e] : (e - E);
    int pos = atomicAdd(&cursor[d], 1);
    eid[rowp[d] + pos] = e;
}

// ---------- GAT layer-1 aggregation: single pass, one wave per dst, 4 heads ----------
// Scores are O(1) => exp without segment-max is numerically identical.
__global__ __launch_bounds__(256)
void gat_agg4_sp(const int* __restrict__ srcs, int E,
                 const int* __restrict__ rowp, const int* __restrict__ eid,
                 const float* __restrict__ as_, const float* __restrict__ ad_,
                 const float* __restrict__ hfeat, const float* __restrict__ bias,
                 float* __restrict__ g, int N) {
    __shared__ float s_alpha[4][64][4];
    const int wave = threadIdx.x >> 6;
    const int lane = threadIdx.x & 63;
    const int head = lane >> 4;
    const int dst = blockIdx.x * 4 + wave;
    if (dst >= N) return;
    const int start = rowp[dst], end = rowp[dst + 1];
    const float4 adv = ((const float4*)ad_)[dst];
    const float4* h4 = (const float4*)hfeat;

    float4 dsum = make_float4(0.f, 0.f, 0.f, 0.f);
    float4 acc  = make_float4(0.f, 0.f, 0.f, 0.f);

    for (int i0 = start; i0 < end; i0 += 64) {
        int cnt = min(64, end - i0);
        int i = i0 + lane;
        int s = 0;
        if (i < end) {
            int e = eid[i];
            s = (e < E) ? srcs[e] : (e - E);
            float4 a = ((const float4*)as_)[s];
            float tx, ex;
            tx = a.x + adv.x; tx = (tx > 0.f) ? tx : NEG_SLOPE * tx; ex = __expf(tx);
            dsum.x += ex; s_alpha[wave][lane][0] = ex;
            tx = a.y + adv.y; tx = (tx > 0.f) ? tx : NEG_SLOPE * tx; ex = __expf(tx);
            dsum.y += ex; s_alpha[wave][lane][1] = ex;
            tx = a.z + adv.z; tx = (tx > 0.f) ? tx : NEG_SLOPE * tx; ex = __expf(tx);
            dsum.z += ex; s_alpha[wave][lane][2] = ex;
            tx = a.w + adv.w; tx = (tx > 0.f) ? tx : NEG_SLOPE * tx; ex = __expf(tx);
            dsum.w += ex; s_alpha[wave][lane][3] = ex;
        }
        __builtin_amdgcn_wave_barrier();
#pragma unroll 4
        for (int k = 0; k < cnt; k++) {
            float a_k = s_alpha[wave][k][head];   // 16-lane broadcast read
            int   s_k = __shfl(s, k);
            float4 hv = h4[(size_t)s_k * 64 + lane];
            acc.x += a_k * hv.x; acc.y += a_k * hv.y;
            acc.z += a_k * hv.z; acc.w += a_k * hv.w;
        }
        __builtin_amdgcn_wave_barrier();
    }
#pragma unroll
    for (int mk = 32; mk >= 1; mk >>= 1) {
        dsum.x += __shfl_xor(dsum.x, mk);
        dsum.y += __shfl_xor(dsum.y, mk);
        dsum.z += __shfl_xor(dsum.z, mk);
        dsum.w += __shfl_xor(dsum.w, mk);
    }
    float den = (head == 0) ? dsum.x : (head == 1) ? dsum.y : (head == 2) ? dsum.z : dsum.w;
    float inv = 1.0f / (den + EPS_A);
    float4 b4 = ((const float4*)bias)[lane];
    float4 r;
    r.x = acc.x * inv + b4.x; r.x = (r.x > 0.f) ? r.x : __expf(r.x) - 1.f;
    r.y = acc.y * inv + b4.y; r.y = (r.y > 0.f) ? r.y : __expf(r.y) - 1.f;
    r.z = acc.z * inv + b4.z; r.z = (r.z > 0.f) ? r.z : __expf(r.z) - 1.f;
    r.w = acc.w * inv + b4.w; r.w = (r.w > 0.f) ? r.w : __expf(r.w) - 1.f;
    ((float4*)g)[(size_t)dst * 64 + lane] = r;
}

// ---------- GAT layer-2 aggregation: single pass, one wave per dst, H=1 ----------
__global__ __launch_bounds__(256)
void gat_agg1_sp(const int* __restrict__ srcs, int E,
                 const int* __restrict__ rowp, const int* __restrict__ eid,
                 const float* __restrict__ as_, const float* __restrict__ ad_,
                 const float* __restrict__ hfeat, const float* __restrict__ bias,
                 float* __restrict__ g, int N) {
    __shared__ float s_alpha[4][64];
    const int wave = threadIdx.x >> 6;
    const int lane = threadIdx.x & 63;
    const int dst = blockIdx.x * 4 + wave;
    if (dst >= N) return;
    const int start = rowp[dst], end = rowp[dst + 1];
    const float adv = ad_[dst];

    float dsum = 0.0f, acc = 0.0f;
    for (int i0 = start; i0 < end; i0 += 64) {
        int cnt = min(64, end - i0);
        int i = i0 + lane;
        int s = 0;
        if (i < end) {
            int e = eid[i];
            s = (e < E) ? srcs[e] : (e - E);
            float t = as_[s] + adv;
            t = (t > 0.f) ? t : NEG_SLOPE * t;
            float ex = __expf(t);
            dsum += ex;
            s_alpha[wave][lane] = ex;
        }
        __builtin_amdgcn_wave_barrier();
#pragma unroll 4
        for (int k = 0; k < cnt; k++) {
            float a_k = s_alpha[wave][k];         // full-wave broadcast read
            int   s_k = __shfl(s, k);
            acc += a_k * hfeat[(size_t)s_k * 64 + lane];
        }
        __builtin_amdgcn_wave_barrier();
    }
#pragma unroll
    for (int mk = 32; mk >= 1; mk >>= 1) dsum += __shfl_xor(dsum, mk);
    g[(size_t)dst * 64 + lane] = acc / (dsum + EPS_A) + bias[lane];
}

// ---------- LSTM via MFMA (split-bf16), round-13 ----------
// Delta vs round 12: the timestep loop is now VMEM-FREE. Each block stages its
// 64-node seq slab (64 x 50 x 3 floats = 38.4 KB) into LDS ONCE, coalesced, at
// kernel start; per-ts x becomes 3 conflict-free ds_read_b32 (col*150 banks
// are 16 distinct; grp duplicates broadcast). Rationale: r8-r12 all landed at
// 335-355us across occupancy 2x / LDS traffic 7x / weights-in-reg-vs-LDS --
// the one invariant was per-ts global x loads inside a barriered loop, and the
// compiler drains vmcnt(0) at every s_barrier (guide s5), exposing L2/HBM
// latency serially in all 50 timesteps. This isolates that term. LDS 56.8 KB.
__global__ __launch_bounds__(512, 4)
void lstm_mfma(const float* __restrict__ seq, const float* __restrict__ Wih,
               const float* __restrict__ Whh, const float* __restrict__ bih,
               const float* __restrict__ bhh, float* __restrict__ t_out, int N) {
    __shared__ float s_seq[9600];           // [node 0..63][t*3+c], 38.4 KB
    __shared__ float s_h[4][2][16][36];     // [pair][pingpong][node][unit+pad] 18 KB

    const int tid  = threadIdx.x;
    const int wave = tid >> 6, lane = tid & 63;
    const int pair = wave >> 1, sub = wave & 1;
    const int grp  = lane >> 4, col = lane & 15;
    const int node0 = blockIdx.x * 64 + pair * 16;

    // ---- stage this block's seq slab (coalesced float4, zero-padded tail) ----
    {
        const size_t base  = (size_t)blockIdx.x * 9600;
        const size_t limit = (size_t)N * 150;
        for (int i = tid * 4; i < 9600; i += 512 * 4) {
            size_t g = base + i;
            float4 v;
            if (g + 3 < limit) {
                v = *(const float4*)&seq[g];
            } else {
                v.x = (g + 0 < limit) ? seq[g + 0] : 0.0f;
                v.y = (g + 1 < limit) ? seq[g + 1] : 0.0f;
                v.z = (g + 2 < limit) ? seq[g + 2] : 0.0f;
                v.w = (g + 3 < limit) ? seq[g + 3] : 0.0f;
            }
            *(float4*)&s_seq[i] = v;
        }
    }

    // ---- weight fragments -> registers (loop-invariant) ----
    // Fragment elem j of lane (grp,col) holds B[n = b*16+col][k' = grp*8+j].
    short8 B2f[4], Bhi[4], Blo[4];
#pragma unroll
    for (int kk = 0; kk < 4; kk++) {
        const int b = sub + kk * 2;          // this wave's gate blocks
        const int n = b * 16 + col;
        const int krow = grp * 8;
        float w[8];
        *(float4*)&w[0] = *(const float4*)&Whh[n * 32 + krow + 0];
        *(float4*)&w[4] = *(const float4*)&Whh[n * 32 + krow + 4];
        short8 hi8, lo8;
#pragma unroll
        for (int j = 0; j < 8; j++) {
            unsigned short h = f2bf(w[j]);
            hi8[j] = (short)h;
            lo8[j] = (short)f2bf(w[j] - bf2f(h));
        }
        Bhi[kk] = hi8;
        Blo[kk] = lo8;
        // B2 (x-path): k'0-2 Wih_hi, 3 bb_hi, k'4-6 Wih_hi, 7 bb_lo, k'8-10 Wih_lo.
        float wi0 = Wih[n * 3 + 0], wi1 = Wih[n * 3 + 1], wi2 = Wih[n * 3 + 2];
        float bb = bih[n] + bhh[n];
        unsigned short h0 = f2bf(wi0), h1 = f2bf(wi1), h2 = f2bf(wi2), hb = f2bf(bb);
        short8 b2 = {0, 0, 0, 0, 0, 0, 0, 0};
        if (grp == 0) {
            b2[0] = (short)h0; b2[1] = (short)h1; b2[2] = (short)h2; b2[3] = (short)hb;
            b2[4] = (short)h0; b2[5] = (short)h1; b2[6] = (short)h2;
            b2[7] = (short)f2bf(bb - bf2f(hb));
        } else if (grp == 1) {
            b2[0] = (short)f2bf(wi0 - bf2f(h0));
            b2[1] = (short)f2bf(wi1 - bf2f(h1));
            b2[2] = (short)f2bf(wi2 - bf2f(h2));
        }
        B2f[kk] = b2;
    }

    // ---- opaque register pin (keeps construction out of the loop where possible) ----
#pragma unroll
    for (int kk = 0; kk < 4; kk++) {
        asm volatile("" : "+v"(B2f[kk]));
        asm volatile("" : "+v"(Bhi[kk]));
        asm volatile("" : "+v"(Blo[kk]));
    }

    for (int i = tid; i < 4 * 2 * 16 * 36; i += 512) ((float*)s_h)[i] = 0.0f;
    __syncthreads();

    float cst[4] = {0.f, 0.f, 0.f, 0.f};
    float hnew[4] = {0.f, 0.f, 0.f, 0.f};
    const floatx4 zac = {0.f, 0.f, 0.f, 0.f};

    const bool g0 = (grp == 0);
    // this lane's x row in LDS (node pair*16+col; all grps read it -- the
    // weight rows for k'>=11 are zero, so grp2/3 contributions vanish).
    const float* xrow = &s_seq[(pair * 16 + col) * 150];

#pragma unroll 1
    for (int t = 0; t < T_STEPS; t++) {
        // ---- x from LDS (conflict-free; grp duplicates broadcast) ----
        float xv0 = xrow[t * 3 + 0];
        float xv1 = xrow[t * 3 + 1];
        float xv2 = xrow[t * 3 + 2];

        // ---- A2: x hi/lo + ones in K-slots (grp0: k'0-7, grp1: k'8-10) ----
        unsigned w0 = cvt_pk_bf16(xv0, xv1);
        unsigned w1 = cvt_pk_bf16(xv2, g0 ? 1.0f : 0.0f);
        float e0 = xv0 - lo16f(w0);
        float e1 = xv1 - hi16f(w0);
        float e2 = xv2 - lo16f(w1);
        unsigned w2 = g0 ? cvt_pk_bf16(e0, e1) : 0u;
        unsigned w3 = g0 ? cvt_pk_bf16(e2, 1.0f) : 0u;
        uint32x4 a2p = {w0, w1, w2, w3};
        short8 A2 = __builtin_bit_cast(short8, a2p);

        // ---- A (h) hi/lo from ping-pong LDS (prev buffer; t=0 reads zeros) ----
        const float* hr = &s_h[pair][(t + 1) & 1][col][grp * 8];
        floatx4 h0 = *(const floatx4*)&hr[0];
        floatx4 h1 = *(const floatx4*)&hr[4];
        unsigned p0 = cvt_pk_bf16(h0[0], h0[1]);
        unsigned p1 = cvt_pk_bf16(h0[2], h0[3]);
        unsigned p2 = cvt_pk_bf16(h1[0], h1[1]);
        unsigned p3 = cvt_pk_bf16(h1[2], h1[3]);
        uint32x4 hip = {p0, p1, p2, p3};
        short8 Ahi = __builtin_bit_cast(short8, hip);
        unsigned q0 = cvt_pk_bf16(h0[0] - lo16f(p0), h0[1] - hi16f(p0));
        unsigned q1 = cvt_pk_bf16(h0[2] - lo16f(p1), h0[3] - hi16f(p1));
        unsigned q2 = cvt_pk_bf16(h1[0] - lo16f(p2), h1[1] - hi16f(p2));
        unsigned q3 = cvt_pk_bf16(h1[2] - lo16f(p3), h1[3] - hi16f(p3));
        uint32x4 lop = {q0, q1, q2, q3};
        short8 Alo = __builtin_bit_cast(short8, lop);

        // ---- this wave's 4 gate-blocks x 4 MFMAs; all operands in registers ----
        floatx4 acc[4];
#pragma unroll
        for (int kk = 0; kk < 4; kk++) {
            floatx4 d = __builtin_amdgcn_mfma_f32_16x16x32_bf16(A2, B2f[kk], zac, 0, 0, 0);
            d = __builtin_amdgcn_mfma_f32_16x16x32_bf16(Alo, Bhi[kk], d, 0, 0, 0);
            d = __builtin_amdgcn_mfma_f32_16x16x32_bf16(Ahi, Blo[kk], d, 0, 0, 0);
            acc[kk] = __builtin_amdgcn_mfma_f32_16x16x32_bf16(Ahi, Bhi[kk], d, 0, 0, 0);
        }

        // ---- gates (this wave's 16 units only) ----
#pragma unroll
        for (int q = 0; q < 4; q++) {
            float ig = sigf(acc[0][q]), fg = sigf(acc[1][q]);
            float gv = tanhfast(acc[2][q]), og = sigf(acc[3][q]);
            cst[q] = fg * cst[q] + ig * gv;
            hnew[q] = og * tanhfast(cst[q]);
        }

        // ---- h writeback to ping-pong buffer, then pair-visible barrier ----
#pragma unroll
        for (int q = 0; q < 4; q++)
            s_h[pair][t & 1][4 * grp + q][sub * 16 + col] = hnew[q];
        __syncthreads();
    }

#pragma unroll
    for (int q = 0; q < 4; q++) {
        int node = node0 + 4 * grp + q;
        if (node < N) t_out[(size_t)node * LSTM_H + sub * 16 + col] = hnew[q];
    }
}

// ---------- fusion MLP ----------
__global__ void fusion_kernel(const float* __restrict__ g2, const float* __restrict__ tt,
                              const float* __restrict__ Wf1, const float* __restrict__ bf1,
                              const float* __restrict__ Wf2, const float* __restrict__ bf2,
                              float* __restrict__ out, int N) {
    __shared__ float sW[96 * 64];
    __shared__ float sb1[64];
    __shared__ float sW2[128];
    for (int i = threadIdx.x; i < 96 * 64; i += 256) sW[i] = Wf1[i];
    if (threadIdx.x < 64) sb1[threadIdx.x] = bf1[threadIdx.x];
    if (threadIdx.x < 128) sW2[threadIdx.x] = Wf2[threadIdx.x];
    __syncthreads();
    const int wave = threadIdx.x >> 6;
    const int lane = threadIdx.x & 63;
    for (int n = blockIdx.x * 4 + wave; n < N; n += gridDim.x * 4) {
        const float* gn = g2 + (size_t)n * 64;
        const float* tn = tt + (size_t)n * 32;
        float acc = sb1[lane];
#pragma unroll 8
        for (int k = 0; k < 64; k++) acc += gn[k] * sW[k * 64 + lane];
#pragma unroll 8
        for (int k = 0; k < 32; k++) acc += tn[k] * sW[(64 + k) * 64 + lane];
        acc = fmaxf(acc, 0.0f);
        float o0 = acc * sW2[lane * 2 + 0];
        float o1 = acc * sW2[lane * 2 + 1];
#pragma unroll
        for (int mk = 32; mk >= 1; mk >>= 1) {
            o0 += __shfl_xor(o0, mk);
            o1 += __shfl_xor(o1, mk);
        }
        if (lane == 0) {
            out[(size_t)n * 2 + 0] = o0 + bf2[0];
            out[(size_t)n * 2 + 1] = o1 + bf2[1];
        }
    }
}

extern "C" void kernel_launch(void* const* d_in, const int* in_sizes, int n_in,
                              void* d_out, int out_size, void* d_ws, size_t ws_size,
                              hipStream_t stream) {
    const float* x      = (const float*)d_in[0];
    const int*   eidx   = (const int*)d_in[1];
    const float* seq    = (const float*)d_in[2];
    const float* W1     = (const float*)d_in[3];
    const float* att_s1 = (const float*)d_in[4];
    const float* att_d1 = (const float*)d_in[5];
    const float* bias1  = (const float*)d_in[6];
    const float* W2     = (const float*)d_in[7];
    const float* att_s2 = (const float*)d_in[8];
    const float* att_d2 = (const float*)d_in[9];
    const float* bias2  = (const float*)d_in[10];
    const float* Wih    = (const float*)d_in[11];
    const float* Whh    = (const float*)d_in[12];
    const float* bih    = (const float*)d_in[13];
    const float* bhh    = (const float*)d_in[14];
    const float* Wf1    = (const float*)d_in[15];
    const float* bf1    = (const float*)d_in[16];
    const float* Wf2    = (const float*)d_in[17];
    const float* bf2    = (const float*)d_in[18];
    float* out = (float*)d_out;

    const int N  = in_sizes[0] / IN_F;   // 50000
    const int E  = in_sizes[1] / 2;      // 800000
    const int ET = E + N;
    const int* srcs = eidx;
    const int* dsts = eidx + E;

    // workspace layout
    float* fws = (float*)d_ws;
    size_t o = 0;
    float* h1  = fws + o; o += (size_t)N * 256;
    float* g1  = fws + o; o += (size_t)N * 256;
    float* as1 = fws + o; o += (size_t)N * 4;
    float* ad1 = fws + o; o += (size_t)N * 4;
    int* cnt    = (int*)(fws + o);
    int* rowp   = cnt + N;
    int* cursor = rowp + N + 1;
    int* eid    = cursor + N;
    int* bsum   = eid + ET;
    // layer-2 / LSTM aliases (h1 region dead after layer-1 aggregation)
    float* h2 = h1;                      // N*64
    float* g2 = h1 + (size_t)N * 64;     // N*64
    float* tt = h1 + (size_t)N * 128;    // N*32
    float* as2 = as1; float* ad2 = ad1;

    const int nTiles = (N + 255) / 256;
    dim3 blk(256);

    // ---- CSR build ----
    hipMemsetAsync(cnt, 0, (size_t)N * sizeof(int), stream);
    hipMemsetAsync(cursor, 0, (size_t)N * sizeof(int), stream);
    count_deg<<<(ET + 255) / 256, blk, 0, stream>>>(dsts, E, ET, cnt);
    scan1<<<nTiles, blk, 0, stream>>>(cnt, rowp, bsum, N);
    scan2<<<1, blk, 0, stream>>>(bsum, nTiles);
    scan3<<<(N + 256) / 256, blk, 0, stream>>>(rowp, bsum, N, ET);
    scatter_edges<<<(ET + 255) / 256, blk, 0, stream>>>(dsts, E, ET, rowp, cursor, eid);

    // ---- GAT layer 1 ----
    gemm64<128, 256><<<dim3((N + 63) / 64, 4), blk, 0, stream>>>(x, W1, h1, N);
    att_scores<<<(N * 4 + 255) / 256, blk, 0, stream>>>(h1, att_s1, att_d1, as1, ad1, N * 4, 3);
    gat_agg4_sp<<<(N + 3) / 4, blk, 0, stream>>>(srcs, E, rowp, eid, as1, ad1, h1, bias1, g1, N);

    // ---- LSTM (MFMA; VMEM-free t-loop via LDS seq slab) ----
    lstm_mfma<<<(N + 63) / 64, dim3(512), 0, stream>>>(seq, Wih, Whh, bih, bhh, tt, N);

    // ---- GAT layer 2 ----
    gemm64<256, 64><<<dim3((N + 63) / 64, 1), blk, 0, stream>>>(g1, W2, h2, N);
    att_scores<<<(N + 255) / 256, blk, 0, stream>>>(h2, att_s2, att_d2, as2, ad2, N, 0);
    gat_agg1_sp<<<(N + 3) / 4, blk, 0, stream>>>(srcs, E, rowp, eid, as2, ad2, h2, bias2, g2, N);

    // ---- fusion MLP ----
    fusion_kernel<<<512, blk, 0, stream>>>(g2, tt, Wf1, bf1, Wf2, bf2, out, N);
}

// Round 6
// 891.024 us; speedup vs baseline: 1.0053x; 1.0053x over previous
//
#include <hip/hip_runtime.h>
#include <math.h>

#define HEADS1 4
#define HID 64
#define LSTM_H 32
#define IN_F 128
#define T_STEPS 50
#define NEG_SLOPE 0.2f
#define EPS_A 1e-16f

typedef __attribute__((ext_vector_type(8))) short short8;
typedef __attribute__((ext_vector_type(4))) float floatx4;
typedef __attribute__((ext_vector_type(4))) unsigned uint32x4;

// ---------- helpers ----------
__device__ __forceinline__ float sigf(float x) { return 1.0f / (1.0f + __expf(-x)); }
__device__ __forceinline__ float tanhfast(float x) {
    float e = __expf(2.0f * x);
    return 1.0f - 2.0f / (e + 1.0f);
}
__device__ __forceinline__ unsigned short f2bf(float f) {
    unsigned u = __float_as_uint(f);
    unsigned r = (u + 0x7FFFu + ((u >> 16) & 1u)) >> 16;
    return (unsigned short)r;
}
__device__ __forceinline__ float bf2f(unsigned short s) {
    return __uint_as_float(((unsigned)s) << 16);
}
// HW packed fp32->bf16 (2 values / instruction); no builtin on gfx950, inline asm.
__device__ __forceinline__ unsigned cvt_pk_bf16(float a, float b) {
    unsigned r;
    asm("v_cvt_pk_bf16_f32 %0, %1, %2" : "=v"(r) : "v"(a), "v"(b));
    return r;
}
__device__ __forceinline__ float lo16f(unsigned p) { return __uint_as_float(p << 16); }
__device__ __forceinline__ float hi16f(unsigned p) { return __uint_as_float(p & 0xffff0000u); }
__device__ __forceinline__ short8 bc8(uint32x4 v) { return __builtin_bit_cast(short8, v); }

// ---------- GEMM: C[M,NC] = A[M,K] @ B[K,NC]; 64x64 tile, 4x4 micro ----------
template <int K, int NC>
__global__ __launch_bounds__(256) void gemm64(const float* __restrict__ A,
                                              const float* __restrict__ B,
                                              float* __restrict__ C, int M) {
    constexpr int KC = 32;
    __shared__ float As[KC][68];
    __shared__ float Bs[KC][64];
    const int row0 = blockIdx.x * 64;
    const int col0 = blockIdx.y * 64;
    const int tx = threadIdx.x & 15;
    const int ty = threadIdx.x >> 4;
    float acc[4][4] = {{0.f}};

    for (int k0 = 0; k0 < K; k0 += KC) {
        {
            const int kk = threadIdx.x & 31;
            const int rb = threadIdx.x >> 5;
#pragma unroll
            for (int r = 0; r < 8; r++) {
                int row = row0 + rb + r * 8;
                As[kk][rb + r * 8] = (row < M) ? A[(size_t)row * K + k0 + kk] : 0.0f;
            }
            const int c  = threadIdx.x & 63;
            const int kb = threadIdx.x >> 6;
#pragma unroll
            for (int q = 0; q < KC / 4; q++)
                Bs[kb + q * 4][c] = B[(size_t)(k0 + kb + q * 4) * NC + col0 + c];
        }
        __syncthreads();
#pragma unroll
        for (int kk = 0; kk < KC; kk++) {
            float4 a4 = *(const float4*)&As[kk][ty * 4];
            float4 b4 = *(const float4*)&Bs[kk][tx * 4];
            float av[4] = {a4.x, a4.y, a4.z, a4.w};
            float bv[4] = {b4.x, b4.y, b4.z, b4.w};
#pragma unroll
            for (int i = 0; i < 4; i++)
#pragma unroll
                for (int j = 0; j < 4; j++) acc[i][j] += av[i] * bv[j];
        }
        __syncthreads();
    }
#pragma unroll
    for (int i = 0; i < 4; i++) {
        int row = row0 + ty * 4 + i;
        if (row < M) {
            float4 v = make_float4(acc[i][0], acc[i][1], acc[i][2], acc[i][3]);
            *(float4*)&C[(size_t)row * NC + col0 + tx * 4] = v;
        }
    }
}

// ---------- attention scores ----------
__global__ void att_scores(const float* __restrict__ h, const float* __restrict__ att_s,
                           const float* __restrict__ att_d, float* __restrict__ as_,
                           float* __restrict__ ad_, int NH, int Hmask) {
    int i = blockIdx.x * blockDim.x + threadIdx.x;
    if (i >= NH) return;
    int hh = i & Hmask;
    const float* row = h + (size_t)i * HID;
    float s = 0.0f, d = 0.0f;
#pragma unroll 8
    for (int c = 0; c < HID; c++) {
        float v = row[c];
        s += v * att_s[hh * HID + c];
        d += v * att_d[hh * HID + c];
    }
    as_[i] = s;
    ad_[i] = d;
}

// ---------- CSR build ----------
__global__ void count_deg(const int* __restrict__ dsts, int E, int ET, int* __restrict__ cnt) {
    int e = blockIdx.x * blockDim.x + threadIdx.x;
    if (e >= ET) return;
    int d = (e < E) ? dsts[e] : (e - E);
    atomicAdd(&cnt[d], 1);
}

__global__ void scan1(const int* __restrict__ cnt, int* __restrict__ rowp,
                      int* __restrict__ bsum, int N) {
    __shared__ int tmp[256];
    int i = blockIdx.x * 256 + threadIdx.x;
    int v = (i < N) ? cnt[i] : 0;
    tmp[threadIdx.x] = v;
    __syncthreads();
    for (int off = 1; off < 256; off <<= 1) {
        int t = (threadIdx.x >= (unsigned)off) ? tmp[threadIdx.x - off] : 0;
        __syncthreads();
        tmp[threadIdx.x] += t;
        __syncthreads();
    }
    if (i < N) rowp[i] = tmp[threadIdx.x] - v;
    if (threadIdx.x == 255) bsum[blockIdx.x] = tmp[255];
}

__global__ void scan2(int* __restrict__ bsum, int nb) {
    __shared__ int tmp[256];
    int v = (threadIdx.x < (unsigned)nb) ? bsum[threadIdx.x] : 0;
    tmp[threadIdx.x] = v;
    __syncthreads();
    for (int off = 1; off < 256; off <<= 1) {
        int t = (threadIdx.x >= (unsigned)off) ? tmp[threadIdx.x - off] : 0;
        __syncthreads();
        tmp[threadIdx.x] += t;
        __syncthreads();
    }
    if (threadIdx.x < (unsigned)nb) bsum[threadIdx.x] = tmp[threadIdx.x] - v;
}

__global__ void scan3(int* __restrict__ rowp, const int* __restrict__ bsum, int N, int ET) {
    int i = blockIdx.x * 256 + threadIdx.x;
    if (i < N) rowp[i] += bsum[blockIdx.x];
    if (i == 0) rowp[N] = ET;
}

__global__ void scatter_edges(const int* __restrict__ dsts, int E, int ET,
                              const int* __restrict__ rowp, int* __restrict__ cursor,
                              int* __restrict__ eid) {
    int e = blockIdx.x * blockDim.x + threadIdx.x;
    if (e >= ET) return;
    int d = (e < E) ? dsts[e] : (e - E);
    int pos = atomicAdd(&cursor[d], 1);
    eid[rowp[d] + pos] = e;
}

// ---------- GAT layer-1 aggregation: single pass, one wave per dst, 4 heads ----------
// Scores are O(1) => exp without segment-max is numerically identical.
__global__ __launch_bounds__(256)
void gat_agg4_sp(const int* __restrict__ srcs, int E,
                 const int* __restrict__ rowp, const int* __restrict__ eid,
                 const float* __restrict__ as_, const float* __restrict__ ad_,
                 const float* __restrict__ hfeat, const float* __restrict__ bias,
                 float* __restrict__ g, int N) {
    __shared__ float s_alpha[4][64][4];
    const int wave = threadIdx.x >> 6;
    const int lane = threadIdx.x & 63;
    const int head = lane >> 4;
    const int dst = blockIdx.x * 4 + wave;
    if (dst >= N) return;
    const int start = rowp[dst], end = rowp[dst + 1];
    const float4 adv = ((const float4*)ad_)[dst];
    const float4* h4 = (const float4*)hfeat;

    float4 dsum = make_float4(0.f, 0.f, 0.f, 0.f);
    float4 acc  = make_float4(0.f, 0.f, 0.f, 0.f);

    for (int i0 = start; i0 < end; i0 += 64) {
        int cnt = min(64, end - i0);
        int i = i0 + lane;
        int s = 0;
        if (i < end) {
            int e = eid[i];
            s = (e < E) ? srcs[e] : (e - E);
            float4 a = ((const float4*)as_)[s];
            float tx, ex;
            tx = a.x + adv.x; tx = (tx > 0.f) ? tx : NEG_SLOPE * tx; ex = __expf(tx);
            dsum.x += ex; s_alpha[wave][lane][0] = ex;
            tx = a.y + adv.y; tx = (tx > 0.f) ? tx : NEG_SLOPE * tx; ex = __expf(tx);
            dsum.y += ex; s_alpha[wave][lane][1] = ex;
            tx = a.z + adv.z; tx = (tx > 0.f) ? tx : NEG_SLOPE * tx; ex = __expf(tx);
            dsum.z += ex; s_alpha[wave][lane][2] = ex;
            tx = a.w + adv.w; tx = (tx > 0.f) ? tx : NEG_SLOPE * tx; ex = __expf(tx);
            dsum.w += ex; s_alpha[wave][lane][3] = ex;
        }
        __builtin_amdgcn_wave_barrier();
#pragma unroll 4
        for (int k = 0; k < cnt; k++) {
            float a_k = s_alpha[wave][k][head];   // 16-lane broadcast read
            int   s_k = __shfl(s, k);
            float4 hv = h4[(size_t)s_k * 64 + lane];
            acc.x += a_k * hv.x; acc.y += a_k * hv.y;
            acc.z += a_k * hv.z; acc.w += a_k * hv.w;
        }
        __builtin_amdgcn_wave_barrier();
    }
#pragma unroll
    for (int mk = 32; mk >= 1; mk >>= 1) {
        dsum.x += __shfl_xor(dsum.x, mk);
        dsum.y += __shfl_xor(dsum.y, mk);
        dsum.z += __shfl_xor(dsum.z, mk);
        dsum.w += __shfl_xor(dsum.w, mk);
    }
    float den = (head == 0) ? dsum.x : (head == 1) ? dsum.y : (head == 2) ? dsum.z : dsum.w;
    float inv = 1.0f / (den + EPS_A);
    float4 b4 = ((const float4*)bias)[lane];
    float4 r;
    r.x = acc.x * inv + b4.x; r.x = (r.x > 0.f) ? r.x : __expf(r.x) - 1.f;
    r.y = acc.y * inv + b4.y; r.y = (r.y > 0.f) ? r.y : __expf(r.y) - 1.f;
    r.z = acc.z * inv + b4.z; r.z = (r.z > 0.f) ? r.z : __expf(r.z) - 1.f;
    r.w = acc.w * inv + b4.w; r.w = (r.w > 0.f) ? r.w : __expf(r.w) - 1.f;
    ((float4*)g)[(size_t)dst * 64 + lane] = r;
}

// ---------- GAT layer-2 aggregation: single pass, one wave per dst, H=1 ----------
__global__ __launch_bounds__(256)
void gat_agg1_sp(const int* __restrict__ srcs, int E,
                 const int* __restrict__ rowp, const int* __restrict__ eid,
                 const float* __restrict__ as_, const float* __restrict__ ad_,
                 const float* __restrict__ hfeat, const float* __restrict__ bias,
                 float* __restrict__ g, int N) {
    __shared__ float s_alpha[4][64];
    const int wave = threadIdx.x >> 6;
    const int lane = threadIdx.x & 63;
    const int dst = blockIdx.x * 4 + wave;
    if (dst >= N) return;
    const int start = rowp[dst], end = rowp[dst + 1];
    const float adv = ad_[dst];

    float dsum = 0.0f, acc = 0.0f;
    for (int i0 = start; i0 < end; i0 += 64) {
        int cnt = min(64, end - i0);
        int i = i0 + lane;
        int s = 0;
        if (i < end) {
            int e = eid[i];
            s = (e < E) ? srcs[e] : (e - E);
            float t = as_[s] + adv;
            t = (t > 0.f) ? t : NEG_SLOPE * t;
            float ex = __expf(t);
            dsum += ex;
            s_alpha[wave][lane] = ex;
        }
        __builtin_amdgcn_wave_barrier();
#pragma unroll 4
        for (int k = 0; k < cnt; k++) {
            float a_k = s_alpha[wave][k];         // full-wave broadcast read
            int   s_k = __shfl(s, k);
            acc += a_k * hfeat[(size_t)s_k * 64 + lane];
        }
        __builtin_amdgcn_wave_barrier();
    }
#pragma unroll
    for (int mk = 32; mk >= 1; mk >>= 1) dsum += __shfl_xor(dsum, mk);
    g[(size_t)dst * 64 + lane] = acc / (dsum + EPS_A) + bias[lane];
}

// ---------- LSTM via MFMA (split-bf16), round-14 ----------
// Delta vs round 13: the 12 weight fragments are NAMED uint32x4 scalars (no
// arrays of ext_vectors -- rule #20: those go to scratch/remat) pinned by ONE
// volatile asm with twelve "+v" operands. r13 post-mortem closed the books:
// wall = ~850 VALU inst/wave-ts (VALUBusy back-solve) vs ~250 static, and
// VGPR_Count=52 across r11-r13 proves the fragments were rebuilt every ts
// (~600 inst of f2bf/pack remat, L2-hit reloads invisible in FETCH). A
// volatile-asm result cannot be rematerialized; at ~105 VGPR needed vs the
// 128 cap of __launch_bounds__(512,4) there is no pressure to spill either.
// VERIFY: VGPR_Count >= 100, WRITE_SIZE == 6250 KB (rise = spill).
__global__ __launch_bounds__(512, 4)
void lstm_mfma(const float* __restrict__ seq, const float* __restrict__ Wih,
               const float* __restrict__ Whh, const float* __restrict__ bih,
               const float* __restrict__ bhh, float* __restrict__ t_out, int N) {
    __shared__ float s_seq[9600];           // [node 0..63][t*3+c], 38.4 KB
    __shared__ float s_h[4][2][16][36];     // [pair][pingpong][node][unit+pad] 18 KB

    const int tid  = threadIdx.x;
    const int wave = tid >> 6, lane = tid & 63;
    const int pair = wave >> 1, sub = wave & 1;
    const int grp  = lane >> 4, col = lane & 15;
    const int node0 = blockIdx.x * 64 + pair * 16;

    // ---- stage this block's seq slab (coalesced float4, zero-padded tail) ----
    {
        const size_t base  = (size_t)blockIdx.x * 9600;
        const size_t limit = (size_t)N * 150;
        for (int i = tid * 4; i < 9600; i += 512 * 4) {
            size_t g = base + i;
            float4 v;
            if (g + 3 < limit) {
                v = *(const float4*)&seq[g];
            } else {
                v.x = (g + 0 < limit) ? seq[g + 0] : 0.0f;
                v.y = (g + 1 < limit) ? seq[g + 1] : 0.0f;
                v.z = (g + 2 < limit) ? seq[g + 2] : 0.0f;
                v.w = (g + 3 < limit) ? seq[g + 3] : 0.0f;
            }
            *(float4*)&s_seq[i] = v;
        }
    }

    // ---- weight fragments: 12 NAMED uint32x4 registers, built once ----
    // Fragment elem j of lane (grp,col) holds B[n = b*16+col][k' = grp*8+j],
    // packed 2 bf16 per u32 (lo = even j).
    uint32x4 B2_0, BH_0, BL_0, B2_1, BH_1, BL_1;
    uint32x4 B2_2, BH_2, BL_2, B2_3, BH_3, BL_3;
    {
        const int krow = grp * 8;
#define BUILD_FRAG(KK, B2V, BHV, BLV)                                          \
        {                                                                      \
            const int n = (sub + (KK) * 2) * 16 + col;                         \
            float w[8];                                                        \
            *(float4*)&w[0] = *(const float4*)&Whh[n * 32 + krow + 0];         \
            *(float4*)&w[4] = *(const float4*)&Whh[n * 32 + krow + 4];         \
            unsigned hi[8], lo[8];                                             \
            _Pragma("unroll")                                                  \
            for (int j = 0; j < 8; j++) {                                      \
                unsigned short hs = f2bf(w[j]);                                \
                hi[j] = hs;                                                    \
                lo[j] = f2bf(w[j] - bf2f(hs));                                 \
            }                                                                  \
            BHV[0] = hi[0] | (hi[1] << 16); BHV[1] = hi[2] | (hi[3] << 16);    \
            BHV[2] = hi[4] | (hi[5] << 16); BHV[3] = hi[6] | (hi[7] << 16);    \
            BLV[0] = lo[0] | (lo[1] << 16); BLV[1] = lo[2] | (lo[3] << 16);    \
            BLV[2] = lo[4] | (lo[5] << 16); BLV[3] = lo[6] | (lo[7] << 16);    \
            float wi0 = Wih[n * 3 + 0], wi1 = Wih[n * 3 + 1], wi2 = Wih[n * 3 + 2]; \
            float bb = bih[n] + bhh[n];                                        \
            unsigned h0 = f2bf(wi0), h1 = f2bf(wi1), h2 = f2bf(wi2), hb = f2bf(bb); \
            B2V[0] = 0u; B2V[1] = 0u; B2V[2] = 0u; B2V[3] = 0u;                \
            if (grp == 0) {                                                    \
                unsigned bl_ = f2bf(bb - bf2f((unsigned short)hb));            \
                B2V[0] = h0 | (h1 << 16); B2V[1] = h2 | (hb << 16);            \
                B2V[2] = h0 | (h1 << 16); B2V[3] = h2 | (bl_ << 16);           \
            } else if (grp == 1) {                                             \
                unsigned l0 = f2bf(wi0 - bf2f((unsigned short)h0));            \
                unsigned l1 = f2bf(wi1 - bf2f((unsigned short)h1));            \
                unsigned l2 = f2bf(wi2 - bf2f((unsigned short)h2));            \
                B2V[0] = l0 | (l1 << 16); B2V[1] = l2;                         \
            }                                                                  \
        }
        BUILD_FRAG(0, B2_0, BH_0, BL_0)
        BUILD_FRAG(1, B2_1, BH_1, BL_1)
        BUILD_FRAG(2, B2_2, BH_2, BL_2)
        BUILD_FRAG(3, B2_3, BH_3, BL_3)
#undef BUILD_FRAG
    }
    // ---- single opaque pin: volatile asm outputs cannot be rematerialized ----
    asm volatile("" : "+v"(B2_0), "+v"(BH_0), "+v"(BL_0),
                      "+v"(B2_1), "+v"(BH_1), "+v"(BL_1),
                      "+v"(B2_2), "+v"(BH_2), "+v"(BL_2),
                      "+v"(B2_3), "+v"(BH_3), "+v"(BL_3));

    for (int i = tid; i < 4 * 2 * 16 * 36; i += 512) ((float*)s_h)[i] = 0.0f;
    __syncthreads();

    float cst0 = 0.f, cst1 = 0.f, cst2 = 0.f, cst3 = 0.f;
    float hn0 = 0.f, hn1 = 0.f, hn2 = 0.f, hn3 = 0.f;
    const floatx4 zac = {0.f, 0.f, 0.f, 0.f};

    const bool g0 = (grp == 0);
    const float* xrow = &s_seq[(pair * 16 + col) * 150];

#pragma unroll 1
    for (int t = 0; t < T_STEPS; t++) {
        // ---- x from LDS (conflict-free; grp duplicates broadcast) ----
        float xv0 = xrow[t * 3 + 0];
        float xv1 = xrow[t * 3 + 1];
        float xv2 = xrow[t * 3 + 2];

        // ---- A2: x hi/lo + ones in K-slots (grp0: k'0-7, grp1: k'8-10) ----
        unsigned w0 = cvt_pk_bf16(xv0, xv1);
        unsigned w1 = cvt_pk_bf16(xv2, g0 ? 1.0f : 0.0f);
        float e0 = xv0 - lo16f(w0);
        float e1 = xv1 - hi16f(w0);
        float e2 = xv2 - lo16f(w1);
        unsigned w2 = g0 ? cvt_pk_bf16(e0, e1) : 0u;
        unsigned w3 = g0 ? cvt_pk_bf16(e2, 1.0f) : 0u;
        uint32x4 a2p = {w0, w1, w2, w3};
        short8 A2 = bc8(a2p);

        // ---- A (h) hi/lo from ping-pong LDS (prev buffer; t=0 reads zeros) ----
        const float* hr = &s_h[pair][(t + 1) & 1][col][grp * 8];
        floatx4 h0 = *(const floatx4*)&hr[0];
        floatx4 h1 = *(const floatx4*)&hr[4];
        unsigned p0 = cvt_pk_bf16(h0[0], h0[1]);
        unsigned p1 = cvt_pk_bf16(h0[2], h0[3]);
        unsigned p2 = cvt_pk_bf16(h1[0], h1[1]);
        unsigned p3 = cvt_pk_bf16(h1[2], h1[3]);
        uint32x4 hip = {p0, p1, p2, p3};
        short8 Ahi = bc8(hip);
        unsigned q0 = cvt_pk_bf16(h0[0] - lo16f(p0), h0[1] - hi16f(p0));
        unsigned q1 = cvt_pk_bf16(h0[2] - lo16f(p1), h0[3] - hi16f(p1));
        unsigned q2 = cvt_pk_bf16(h1[0] - lo16f(p2), h1[1] - hi16f(p2));
        unsigned q3 = cvt_pk_bf16(h1[2] - lo16f(p3), h1[3] - hi16f(p3));
        uint32x4 lop = {q0, q1, q2, q3};
        short8 Alo = bc8(lop);

        // ---- 4 gate-blocks x 4 MFMAs; all operands in named registers ----
        floatx4 d0 = __builtin_amdgcn_mfma_f32_16x16x32_bf16(A2, bc8(B2_0), zac, 0, 0, 0);
        d0 = __builtin_amdgcn_mfma_f32_16x16x32_bf16(Alo, bc8(BH_0), d0, 0, 0, 0);
        d0 = __builtin_amdgcn_mfma_f32_16x16x32_bf16(Ahi, bc8(BL_0), d0, 0, 0, 0);
        d0 = __builtin_amdgcn_mfma_f32_16x16x32_bf16(Ahi, bc8(BH_0), d0, 0, 0, 0);
        floatx4 d1 = __builtin_amdgcn_mfma_f32_16x16x32_bf16(A2, bc8(B2_1), zac, 0, 0, 0);
        d1 = __builtin_amdgcn_mfma_f32_16x16x32_bf16(Alo, bc8(BH_1), d1, 0, 0, 0);
        d1 = __builtin_amdgcn_mfma_f32_16x16x32_bf16(Ahi, bc8(BL_1), d1, 0, 0, 0);
        d1 = __builtin_amdgcn_mfma_f32_16x16x32_bf16(Ahi, bc8(BH_1), d1, 0, 0, 0);
        floatx4 d2 = __builtin_amdgcn_mfma_f32_16x16x32_bf16(A2, bc8(B2_2), zac, 0, 0, 0);
        d2 = __builtin_amdgcn_mfma_f32_16x16x32_bf16(Alo, bc8(BH_2), d2, 0, 0, 0);
        d2 = __builtin_amdgcn_mfma_f32_16x16x32_bf16(Ahi, bc8(BL_2), d2, 0, 0, 0);
        d2 = __builtin_amdgcn_mfma_f32_16x16x32_bf16(Ahi, bc8(BH_2), d2, 0, 0, 0);
        floatx4 d3 = __builtin_amdgcn_mfma_f32_16x16x32_bf16(A2, bc8(B2_3), zac, 0, 0, 0);
        d3 = __builtin_amdgcn_mfma_f32_16x16x32_bf16(Alo, bc8(BH_3), d3, 0, 0, 0);
        d3 = __builtin_amdgcn_mfma_f32_16x16x32_bf16(Ahi, bc8(BL_3), d3, 0, 0, 0);
        d3 = __builtin_amdgcn_mfma_f32_16x16x32_bf16(Ahi, bc8(BH_3), d3, 0, 0, 0);

        // ---- gates: d0=i, d1=f, d2=g, d3=o; per-q unrolled, named state ----
        {
            float ig, fg, gv, og;
            ig = sigf(d0[0]); fg = sigf(d1[0]); gv = tanhfast(d2[0]); og = sigf(d3[0]);
            cst0 = fg * cst0 + ig * gv; hn0 = og * tanhfast(cst0);
            ig = sigf(d0[1]); fg = sigf(d1[1]); gv = tanhfast(d2[1]); og = sigf(d3[1]);
            cst1 = fg * cst1 + ig * gv; hn1 = og * tanhfast(cst1);
            ig = sigf(d0[2]); fg = sigf(d1[2]); gv = tanhfast(d2[2]); og = sigf(d3[2]);
            cst2 = fg * cst2 + ig * gv; hn2 = og * tanhfast(cst2);
            ig = sigf(d0[3]); fg = sigf(d1[3]); gv = tanhfast(d2[3]); og = sigf(d3[3]);
            cst3 = fg * cst3 + ig * gv; hn3 = og * tanhfast(cst3);
        }

        // ---- h writeback to ping-pong buffer, then pair-visible barrier ----
        float* hw = &s_h[pair][t & 1][4 * grp][sub * 16 + col];
        hw[0 * 36] = hn0; hw[1 * 36] = hn1; hw[2 * 36] = hn2; hw[3 * 36] = hn3;
        __syncthreads();
    }

    {
        int node = node0 + 4 * grp;
        const int c = sub * 16 + col;
        if (node + 0 < N) t_out[(size_t)(node + 0) * LSTM_H + c] = hn0;
        if (node + 1 < N) t_out[(size_t)(node + 1) * LSTM_H + c] = hn1;
        if (node + 2 < N) t_out[(size_t)(node + 2) * LSTM_H + c] = hn2;
        if (node + 3 < N) t_out[(size_t)(node + 3) * LSTM_H + c] = hn3;
    }
}

// ---------- fusion MLP ----------
__global__ void fusion_kernel(const float* __restrict__ g2, const float* __restrict__ tt,
                              const float* __restrict__ Wf1, const float* __restrict__ bf1,
                              const float* __restrict__ Wf2, const float* __restrict__ bf2,
                              float* __restrict__ out, int N) {
    __shared__ float sW[96 * 64];
    __shared__ float sb1[64];
    __shared__ float sW2[128];
    for (int i = threadIdx.x; i < 96 * 64; i += 256) sW[i] = Wf1[i];
    if (threadIdx.x < 64) sb1[threadIdx.x] = bf1[threadIdx.x];
    if (threadIdx.x < 128) sW2[threadIdx.x] = Wf2[threadIdx.x];
    __syncthreads();
    const int wave = threadIdx.x >> 6;
    const int lane = threadIdx.x & 63;
    for (int n = blockIdx.x * 4 + wave; n < N; n += gridDim.x * 4) {
        const float* gn = g2 + (size_t)n * 64;
        const float* tn = tt + (size_t)n * 32;
        float acc = sb1[lane];
#pragma unroll 8
        for (int k = 0; k < 64; k++) acc += gn[k] * sW[k * 64 + lane];
#pragma unroll 8
        for (int k = 0; k < 32; k++) acc += tn[k] * sW[(64 + k) * 64 + lane];
        acc = fmaxf(acc, 0.0f);
        float o0 = acc * sW2[lane * 2 + 0];
        float o1 = acc * sW2[lane * 2 + 1];
#pragma unroll
        for (int mk = 32; mk >= 1; mk >>= 1) {
            o0 += __shfl_xor(o0, mk);
            o1 += __shfl_xor(o1, mk);
        }
        if (lane == 0) {
            out[(size_t)n * 2 + 0] = o0 + bf2[0];
            out[(size_t)n * 2 + 1] = o1 + bf2[1];
        }
    }
}

extern "C" void kernel_launch(void* const* d_in, const int* in_sizes, int n_in,
                              void* d_out, int out_size, void* d_ws, size_t ws_size,
                              hipStream_t stream) {
    const float* x      = (const float*)d_in[0];
    const int*   eidx   = (const int*)d_in[1];
    const float* seq    = (const float*)d_in[2];
    const float* W1     = (const float*)d_in[3];
    const float* att_s1 = (const float*)d_in[4];
    const float* att_d1 = (const float*)d_in[5];
    const float* bias1  = (const float*)d_in[6];
    const float* W2     = (const float*)d_in[7];
    const float* att_s2 = (const float*)d_in[8];
    const float* att_d2 = (const float*)d_in[9];
    const float* bias2  = (const float*)d_in[10];
    const float* Wih    = (const float*)d_in[11];
    const float* Whh    = (const float*)d_in[12];
    const float* bih    = (const float*)d_in[13];
    const float* bhh    = (const float*)d_in[14];
    const float* Wf1    = (const float*)d_in[15];
    const float* bf1    = (const float*)d_in[16];
    const float* Wf2    = (const float*)d_in[17];
    const float* bf2    = (const float*)d_in[18];
    float* out = (float*)d_out;

    const int N  = in_sizes[0] / IN_F;   // 50000
    const int E  = in_sizes[1] / 2;      // 800000
    const int ET = E + N;
    const int* srcs = eidx;
    const int* dsts = eidx + E;

    // workspace layout
    float* fws = (float*)d_ws;
    size_t o = 0;
    float* h1  = fws + o; o += (size_t)N * 256;
    float* g1  = fws + o; o += (size_t)N * 256;
    float* as1 = fws + o; o += (size_t)N * 4;
    float* ad1 = fws + o; o += (size_t)N * 4;
    int* cnt    = (int*)(fws + o);
    int* rowp   = cnt + N;
    int* cursor = rowp + N + 1;
    int* eid    = cursor + N;
    int* bsum   = eid + ET;
    // layer-2 / LSTM aliases (h1 region dead after layer-1 aggregation)
    float* h2 = h1;                      // N*64
    float* g2 = h1 + (size_t)N * 64;     // N*64
    float* tt = h1 + (size_t)N * 128;    // N*32
    float* as2 = as1; float* ad2 = ad1;

    const int nTiles = (N + 255) / 256;
    dim3 blk(256);

    // ---- CSR build ----
    hipMemsetAsync(cnt, 0, (size_t)N * sizeof(int), stream);
    hipMemsetAsync(cursor, 0, (size_t)N * sizeof(int), stream);
    count_deg<<<(ET + 255) / 256, blk, 0, stream>>>(dsts, E, ET, cnt);
    scan1<<<nTiles, blk, 0, stream>>>(cnt, rowp, bsum, N);
    scan2<<<1, blk, 0, stream>>>(bsum, nTiles);
    scan3<<<(N + 256) / 256, blk, 0, stream>>>(rowp, bsum, N, ET);
    scatter_edges<<<(ET + 255) / 256, blk, 0, stream>>>(dsts, E, ET, rowp, cursor, eid);

    // ---- GAT layer 1 ----
    gemm64<128, 256><<<dim3((N + 63) / 64, 4), blk, 0, stream>>>(x, W1, h1, N);
    att_scores<<<(N * 4 + 255) / 256, blk, 0, stream>>>(h1, att_s1, att_d1, as1, ad1, N * 4, 3);
    gat_agg4_sp<<<(N + 3) / 4, blk, 0, stream>>>(srcs, E, rowp, eid, as1, ad1, h1, bias1, g1, N);

    // ---- LSTM (MFMA; named+pinned reg weights; VMEM-free t-loop) ----
    lstm_mfma<<<(N + 63) / 64, dim3(512), 0, stream>>>(seq, Wih, Whh, bih, bhh, tt, N);

    // ---- GAT layer 2 ----
    gemm64<256, 64><<<dim3((N + 63) / 64, 1), blk, 0, stream>>>(g1, W2, h2, N);
    att_scores<<<(N + 255) / 256, blk, 0, stream>>>(h2, att_s2, att_d2, as2, ad2, N, 0);
    gat_agg1_sp<<<(N + 3) / 4, blk, 0, stream>>>(srcs, E, rowp, eid, as2, ad2, h2, bias2, g2, N);

    // ---- fusion MLP ----
    fusion_kernel<<<512, blk, 0, stream>>>(g2, tt, Wf1, bf1, Wf2, bf2, out, N);
}

// Round 7
// 877.558 us; speedup vs baseline: 1.0207x; 1.0153x over previous
//
#include <hip/hip_runtime.h>
#include <math.h>

#define HEADS1 4
#define HID 64
#define LSTM_H 32
#define IN_F 128
#define T_STEPS 50
#define NEG_SLOPE 0.2f
#define EPS_A 1e-16f

typedef __attribute__((ext_vector_type(8))) short short8;
typedef __attribute__((ext_vector_type(4))) float floatx4;
typedef __attribute__((ext_vector_type(4))) unsigned uint32x4;

// ---------- helpers ----------
__device__ __forceinline__ float sigf(float x) { return 1.0f / (1.0f + __expf(-x)); }
__device__ __forceinline__ float tanhfast(float x) {
    float e = __expf(2.0f * x);
    return 1.0f - 2.0f / (e + 1.0f);
}
__device__ __forceinline__ unsigned short f2bf(float f) {
    unsigned u = __float_as_uint(f);
    unsigned r = (u + 0x7FFFu + ((u >> 16) & 1u)) >> 16;
    return (unsigned short)r;
}
__device__ __forceinline__ float bf2f(unsigned short s) {
    return __uint_as_float(((unsigned)s) << 16);
}
// HW packed fp32->bf16 (2 values / instruction); no builtin on gfx950, inline asm.
__device__ __forceinline__ unsigned cvt_pk_bf16(float a, float b) {
    unsigned r;
    asm("v_cvt_pk_bf16_f32 %0, %1, %2" : "=v"(r) : "v"(a), "v"(b));
    return r;
}
__device__ __forceinline__ float lo16f(unsigned p) { return __uint_as_float(p << 16); }
__device__ __forceinline__ float hi16f(unsigned p) { return __uint_as_float(p & 0xffff0000u); }
__device__ __forceinline__ short8 bc8(uint32x4 v) { return __builtin_bit_cast(short8, v); }

// ---------- GEMM: C[M,NC] = A[M,K] @ B[K,NC]; 64x64 tile, 4x4 micro ----------
template <int K, int NC>
__global__ __launch_bounds__(256) void gemm64(const float* __restrict__ A,
                                              const float* __restrict__ B,
                                              float* __restrict__ C, int M) {
    constexpr int KC = 32;
    __shared__ float As[KC][68];
    __shared__ float Bs[KC][64];
    const int row0 = blockIdx.x * 64;
    const int col0 = blockIdx.y * 64;
    const int tx = threadIdx.x & 15;
    const int ty = threadIdx.x >> 4;
    float acc[4][4] = {{0.f}};

    for (int k0 = 0; k0 < K; k0 += KC) {
        {
            const int kk = threadIdx.x & 31;
            const int rb = threadIdx.x >> 5;
#pragma unroll
            for (int r = 0; r < 8; r++) {
                int row = row0 + rb + r * 8;
                As[kk][rb + r * 8] = (row < M) ? A[(size_t)row * K + k0 + kk] : 0.0f;
            }
            const int c  = threadIdx.x & 63;
            const int kb = threadIdx.x >> 6;
#pragma unroll
            for (int q = 0; q < KC / 4; q++)
                Bs[kb + q * 4][c] = B[(size_t)(k0 + kb + q * 4) * NC + col0 + c];
        }
        __syncthreads();
#pragma unroll
        for (int kk = 0; kk < KC; kk++) {
            float4 a4 = *(const float4*)&As[kk][ty * 4];
            float4 b4 = *(const float4*)&Bs[kk][tx * 4];
            float av[4] = {a4.x, a4.y, a4.z, a4.w};
            float bv[4] = {b4.x, b4.y, b4.z, b4.w};
#pragma unroll
            for (int i = 0; i < 4; i++)
#pragma unroll
                for (int j = 0; j < 4; j++) acc[i][j] += av[i] * bv[j];
        }
        __syncthreads();
    }
#pragma unroll
    for (int i = 0; i < 4; i++) {
        int row = row0 + ty * 4 + i;
        if (row < M) {
            float4 v = make_float4(acc[i][0], acc[i][1], acc[i][2], acc[i][3]);
            *(float4*)&C[(size_t)row * NC + col0 + tx * 4] = v;
        }
    }
}

// ---------- attention scores ----------
__global__ void att_scores(const float* __restrict__ h, const float* __restrict__ att_s,
                           const float* __restrict__ att_d, float* __restrict__ as_,
                           float* __restrict__ ad_, int NH, int Hmask) {
    int i = blockIdx.x * blockDim.x + threadIdx.x;
    if (i >= NH) return;
    int hh = i & Hmask;
    const float* row = h + (size_t)i * HID;
    float s = 0.0f, d = 0.0f;
#pragma unroll 8
    for (int c = 0; c < HID; c++) {
        float v = row[c];
        s += v * att_s[hh * HID + c];
        d += v * att_d[hh * HID + c];
    }
    as_[i] = s;
    ad_[i] = d;
}

// ---------- CSR build ----------
__global__ void count_deg(const int* __restrict__ dsts, int E, int ET, int* __restrict__ cnt) {
    int e = blockIdx.x * blockDim.x + threadIdx.x;
    if (e >= ET) return;
    int d = (e < E) ? dsts[e] : (e - E);
    atomicAdd(&cnt[d], 1);
}

__global__ void scan1(const int* __restrict__ cnt, int* __restrict__ rowp,
                      int* __restrict__ bsum, int N) {
    __shared__ int tmp[256];
    int i = blockIdx.x * 256 + threadIdx.x;
    int v = (i < N) ? cnt[i] : 0;
    tmp[threadIdx.x] = v;
    __syncthreads();
    for (int off = 1; off < 256; off <<= 1) {
        int t = (threadIdx.x >= (unsigned)off) ? tmp[threadIdx.x - off] : 0;
        __syncthreads();
        tmp[threadIdx.x] += t;
        __syncthreads();
    }
    if (i < N) rowp[i] = tmp[threadIdx.x] - v;
    if (threadIdx.x == 255) bsum[blockIdx.x] = tmp[255];
}

__global__ void scan2(int* __restrict__ bsum, int nb) {
    __shared__ int tmp[256];
    int v = (threadIdx.x < (unsigned)nb) ? bsum[threadIdx.x] : 0;
    tmp[threadIdx.x] = v;
    __syncthreads();
    for (int off = 1; off < 256; off <<= 1) {
        int t = (threadIdx.x >= (unsigned)off) ? tmp[threadIdx.x - off] : 0;
        __syncthreads();
        tmp[threadIdx.x] += t;
        __syncthreads();
    }
    if (threadIdx.x < (unsigned)nb) bsum[threadIdx.x] = tmp[threadIdx.x] - v;
}

__global__ void scan3(int* __restrict__ rowp, const int* __restrict__ bsum, int N, int ET) {
    int i = blockIdx.x * 256 + threadIdx.x;
    if (i < N) rowp[i] += bsum[blockIdx.x];
    if (i == 0) rowp[N] = ET;
}

__global__ void scatter_edges(const int* __restrict__ dsts, int E, int ET,
                              const int* __restrict__ rowp, int* __restrict__ cursor,
                              int* __restrict__ eid) {
    int e = blockIdx.x * blockDim.x + threadIdx.x;
    if (e >= ET) return;
    int d = (e < E) ? dsts[e] : (e - E);
    int pos = atomicAdd(&cursor[d], 1);
    eid[rowp[d] + pos] = e;
}

// ---------- GAT layer-1 aggregation: single pass, one wave per dst, 4 heads ----------
// Scores are O(1) => exp without segment-max is numerically identical.
__global__ __launch_bounds__(256)
void gat_agg4_sp(const int* __restrict__ srcs, int E,
                 const int* __restrict__ rowp, const int* __restrict__ eid,
                 const float* __restrict__ as_, const float* __restrict__ ad_,
                 const float* __restrict__ hfeat, const float* __restrict__ bias,
                 float* __restrict__ g, int N) {
    __shared__ float s_alpha[4][64][4];
    const int wave = threadIdx.x >> 6;
    const int lane = threadIdx.x & 63;
    const int head = lane >> 4;
    const int dst = blockIdx.x * 4 + wave;
    if (dst >= N) return;
    const int start = rowp[dst], end = rowp[dst + 1];
    const float4 adv = ((const float4*)ad_)[dst];
    const float4* h4 = (const float4*)hfeat;

    float4 dsum = make_float4(0.f, 0.f, 0.f, 0.f);
    float4 acc  = make_float4(0.f, 0.f, 0.f, 0.f);

    for (int i0 = start; i0 < end; i0 += 64) {
        int cnt = min(64, end - i0);
        int i = i0 + lane;
        int s = 0;
        if (i < end) {
            int e = eid[i];
            s = (e < E) ? srcs[e] : (e - E);
            float4 a = ((const float4*)as_)[s];
            float tx, ex;
            tx = a.x + adv.x; tx = (tx > 0.f) ? tx : NEG_SLOPE * tx; ex = __expf(tx);
            dsum.x += ex; s_alpha[wave][lane][0] = ex;
            tx = a.y + adv.y; tx = (tx > 0.f) ? tx : NEG_SLOPE * tx; ex = __expf(tx);
            dsum.y += ex; s_alpha[wave][lane][1] = ex;
            tx = a.z + adv.z; tx = (tx > 0.f) ? tx : NEG_SLOPE * tx; ex = __expf(tx);
            dsum.z += ex; s_alpha[wave][lane][2] = ex;
            tx = a.w + adv.w; tx = (tx > 0.f) ? tx : NEG_SLOPE * tx; ex = __expf(tx);
            dsum.w += ex; s_alpha[wave][lane][3] = ex;
        }
        __builtin_amdgcn_wave_barrier();
#pragma unroll 4
        for (int k = 0; k < cnt; k++) {
            float a_k = s_alpha[wave][k][head];   // 16-lane broadcast read
            int   s_k = __shfl(s, k);
            float4 hv = h4[(size_t)s_k * 64 + lane];
            acc.x += a_k * hv.x; acc.y += a_k * hv.y;
            acc.z += a_k * hv.z; acc.w += a_k * hv.w;
        }
        __builtin_amdgcn_wave_barrier();
    }
#pragma unroll
    for (int mk = 32; mk >= 1; mk >>= 1) {
        dsum.x += __shfl_xor(dsum.x, mk);
        dsum.y += __shfl_xor(dsum.y, mk);
        dsum.z += __shfl_xor(dsum.z, mk);
        dsum.w += __shfl_xor(dsum.w, mk);
    }
    float den = (head == 0) ? dsum.x : (head == 1) ? dsum.y : (head == 2) ? dsum.z : dsum.w;
    float inv = 1.0f / (den + EPS_A);
    float4 b4 = ((const float4*)bias)[lane];
    float4 r;
    r.x = acc.x * inv + b4.x; r.x = (r.x > 0.f) ? r.x : __expf(r.x) - 1.f;
    r.y = acc.y * inv + b4.y; r.y = (r.y > 0.f) ? r.y : __expf(r.y) - 1.f;
    r.z = acc.z * inv + b4.z; r.z = (r.z > 0.f) ? r.z : __expf(r.z) - 1.f;
    r.w = acc.w * inv + b4.w; r.w = (r.w > 0.f) ? r.w : __expf(r.w) - 1.f;
    ((float4*)g)[(size_t)dst * 64 + lane] = r;
}

// ---------- GAT layer-2 aggregation: single pass, one wave per dst, H=1 ----------
__global__ __launch_bounds__(256)
void gat_agg1_sp(const int* __restrict__ srcs, int E,
                 const int* __restrict__ rowp, const int* __restrict__ eid,
                 const float* __restrict__ as_, const float* __restrict__ ad_,
                 const float* __restrict__ hfeat, const float* __restrict__ bias,
                 float* __restrict__ g, int N) {
    __shared__ float s_alpha[4][64];
    const int wave = threadIdx.x >> 6;
    const int lane = threadIdx.x & 63;
    const int dst = blockIdx.x * 4 + wave;
    if (dst >= N) return;
    const int start = rowp[dst], end = rowp[dst + 1];
    const float adv = ad_[dst];

    float dsum = 0.0f, acc = 0.0f;
    for (int i0 = start; i0 < end; i0 += 64) {
        int cnt = min(64, end - i0);
        int i = i0 + lane;
        int s = 0;
        if (i < end) {
            int e = eid[i];
            s = (e < E) ? srcs[e] : (e - E);
            float t = as_[s] + adv;
            t = (t > 0.f) ? t : NEG_SLOPE * t;
            float ex = __expf(t);
            dsum += ex;
            s_alpha[wave][lane] = ex;
        }
        __builtin_amdgcn_wave_barrier();
#pragma unroll 4
        for (int k = 0; k < cnt; k++) {
            float a_k = s_alpha[wave][k];         // full-wave broadcast read
            int   s_k = __shfl(s, k);
            acc += a_k * hfeat[(size_t)s_k * 64 + lane];
        }
        __builtin_amdgcn_wave_barrier();
    }
#pragma unroll
    for (int mk = 32; mk >= 1; mk >>= 1) dsum += __shfl_xor(dsum, mk);
    g[(size_t)dst * 64 + lane] = acc / (dsum + EPS_A) + bias[lane];
}

// ---------- LSTM via MFMA (split-bf16), round-15 ----------
// Delta vs round 14: ONE attribute -- amdgpu_waves_per_eu(2,4). Post-mortem of
// r9-r14: the allocator landed at <=64 VGPR in EVERY round (64/40/52/52/52/52)
// = the 8-waves-per-EU occupancy target. __launch_bounds__'s 2nd arg only sets
// a register CAP (512/min_waves); the AMDGPU allocator's heuristic still aims
// for MAX waves/EU (8 -> 64 regs) and pays spill-to-scratch restores of the
// pinned fragments every timestep to get there (scratch is L2-resident ->
// invisible in FETCH/WRITE; cost ~= r10's LDS weight reads, which is why all
// variants cost ~336us). But LDS caps residency at 2 blocks/CU = 4 waves/EU,
// so that occupancy is unbuyable -- pure loss. amdgpu_waves_per_eu(2,4) sets
// max=4: allocator budget becomes 128 regs, live set (~105) fits, no restore.
// VERIFY: VGPR_Count ~100-128 (<=64 => attribute failed); WRITE_SIZE 6250.
__global__ __launch_bounds__(512)
__attribute__((amdgpu_waves_per_eu(2, 4)))
void lstm_mfma(const float* __restrict__ seq, const float* __restrict__ Wih,
               const float* __restrict__ Whh, const float* __restrict__ bih,
               const float* __restrict__ bhh, float* __restrict__ t_out, int N) {
    __shared__ float s_seq[9600];           // [node 0..63][t*3+c], 38.4 KB
    __shared__ float s_h[4][2][16][36];     // [pair][pingpong][node][unit+pad] 18 KB

    const int tid  = threadIdx.x;
    const int wave = tid >> 6, lane = tid & 63;
    const int pair = wave >> 1, sub = wave & 1;
    const int grp  = lane >> 4, col = lane & 15;
    const int node0 = blockIdx.x * 64 + pair * 16;

    // ---- stage this block's seq slab (coalesced float4, zero-padded tail) ----
    {
        const size_t base  = (size_t)blockIdx.x * 9600;
        const size_t limit = (size_t)N * 150;
        for (int i = tid * 4; i < 9600; i += 512 * 4) {
            size_t g = base + i;
            float4 v;
            if (g + 3 < limit) {
                v = *(const float4*)&seq[g];
            } else {
                v.x = (g + 0 < limit) ? seq[g + 0] : 0.0f;
                v.y = (g + 1 < limit) ? seq[g + 1] : 0.0f;
                v.z = (g + 2 < limit) ? seq[g + 2] : 0.0f;
                v.w = (g + 3 < limit) ? seq[g + 3] : 0.0f;
            }
            *(float4*)&s_seq[i] = v;
        }
    }

    // ---- weight fragments: 12 NAMED uint32x4 registers, built once ----
    // Fragment elem j of lane (grp,col) holds B[n = b*16+col][k' = grp*8+j],
    // packed 2 bf16 per u32 (lo = even j).
    uint32x4 B2_0, BH_0, BL_0, B2_1, BH_1, BL_1;
    uint32x4 B2_2, BH_2, BL_2, B2_3, BH_3, BL_3;
    {
        const int krow = grp * 8;
#define BUILD_FRAG(KK, B2V, BHV, BLV)                                          \
        {                                                                      \
            const int n = (sub + (KK) * 2) * 16 + col;                         \
            float w[8];                                                        \
            *(float4*)&w[0] = *(const float4*)&Whh[n * 32 + krow + 0];         \
            *(float4*)&w[4] = *(const float4*)&Whh[n * 32 + krow + 4];         \
            unsigned hi[8], lo[8];                                             \
            _Pragma("unroll")                                                  \
            for (int j = 0; j < 8; j++) {                                      \
                unsigned short hs = f2bf(w[j]);                                \
                hi[j] = hs;                                                    \
                lo[j] = f2bf(w[j] - bf2f(hs));                                 \
            }                                                                  \
            BHV[0] = hi[0] | (hi[1] << 16); BHV[1] = hi[2] | (hi[3] << 16);    \
            BHV[2] = hi[4] | (hi[5] << 16); BHV[3] = hi[6] | (hi[7] << 16);    \
            BLV[0] = lo[0] | (lo[1] << 16); BLV[1] = lo[2] | (lo[3] << 16);    \
            BLV[2] = lo[4] | (lo[5] << 16); BLV[3] = lo[6] | (lo[7] << 16);    \
            float wi0 = Wih[n * 3 + 0], wi1 = Wih[n * 3 + 1], wi2 = Wih[n * 3 + 2]; \
            float bb = bih[n] + bhh[n];                                        \
            unsigned h0 = f2bf(wi0), h1 = f2bf(wi1), h2 = f2bf(wi2), hb = f2bf(bb); \
            B2V[0] = 0u; B2V[1] = 0u; B2V[2] = 0u; B2V[3] = 0u;                \
            if (grp == 0) {                                                    \
                unsigned bl_ = f2bf(bb - bf2f((unsigned short)hb));            \
                B2V[0] = h0 | (h1 << 16); B2V[1] = h2 | (hb << 16);            \
                B2V[2] = h0 | (h1 << 16); B2V[3] = h2 | (bl_ << 16);           \
            } else if (grp == 1) {                                             \
                unsigned l0 = f2bf(wi0 - bf2f((unsigned short)h0));            \
                unsigned l1 = f2bf(wi1 - bf2f((unsigned short)h1));            \
                unsigned l2 = f2bf(wi2 - bf2f((unsigned short)h2));            \
                B2V[0] = l0 | (l1 << 16); B2V[1] = l2;                         \
            }                                                                  \
        }
        BUILD_FRAG(0, B2_0, BH_0, BL_0)
        BUILD_FRAG(1, B2_1, BH_1, BL_1)
        BUILD_FRAG(2, B2_2, BH_2, BL_2)
        BUILD_FRAG(3, B2_3, BH_3, BL_3)
#undef BUILD_FRAG
    }
    // ---- single opaque pin: volatile asm outputs cannot be rematerialized ----
    asm volatile("" : "+v"(B2_0), "+v"(BH_0), "+v"(BL_0),
                      "+v"(B2_1), "+v"(BH_1), "+v"(BL_1),
                      "+v"(B2_2), "+v"(BH_2), "+v"(BL_2),
                      "+v"(B2_3), "+v"(BH_3), "+v"(BL_3));

    for (int i = tid; i < 4 * 2 * 16 * 36; i += 512) ((float*)s_h)[i] = 0.0f;
    __syncthreads();

    float cst0 = 0.f, cst1 = 0.f, cst2 = 0.f, cst3 = 0.f;
    float hn0 = 0.f, hn1 = 0.f, hn2 = 0.f, hn3 = 0.f;
    const floatx4 zac = {0.f, 0.f, 0.f, 0.f};

    const bool g0 = (grp == 0);
    const float* xrow = &s_seq[(pair * 16 + col) * 150];

#pragma unroll 1
    for (int t = 0; t < T_STEPS; t++) {
        // ---- x from LDS (conflict-free; grp duplicates broadcast) ----
        float xv0 = xrow[t * 3 + 0];
        float xv1 = xrow[t * 3 + 1];
        float xv2 = xrow[t * 3 + 2];

        // ---- A2: x hi/lo + ones in K-slots (grp0: k'0-7, grp1: k'8-10) ----
        unsigned w0 = cvt_pk_bf16(xv0, xv1);
        unsigned w1 = cvt_pk_bf16(xv2, g0 ? 1.0f : 0.0f);
        float e0 = xv0 - lo16f(w0);
        float e1 = xv1 - hi16f(w0);
        float e2 = xv2 - lo16f(w1);
        unsigned w2 = g0 ? cvt_pk_bf16(e0, e1) : 0u;
        unsigned w3 = g0 ? cvt_pk_bf16(e2, 1.0f) : 0u;
        uint32x4 a2p = {w0, w1, w2, w3};
        short8 A2 = bc8(a2p);

        // ---- A (h) hi/lo from ping-pong LDS (prev buffer; t=0 reads zeros) ----
        const float* hr = &s_h[pair][(t + 1) & 1][col][grp * 8];
        floatx4 h0 = *(const floatx4*)&hr[0];
        floatx4 h1 = *(const floatx4*)&hr[4];
        unsigned p0 = cvt_pk_bf16(h0[0], h0[1]);
        unsigned p1 = cvt_pk_bf16(h0[2], h0[3]);
        unsigned p2 = cvt_pk_bf16(h1[0], h1[1]);
        unsigned p3 = cvt_pk_bf16(h1[2], h1[3]);
        uint32x4 hip = {p0, p1, p2, p3};
        short8 Ahi = bc8(hip);
        unsigned q0 = cvt_pk_bf16(h0[0] - lo16f(p0), h0[1] - hi16f(p0));
        unsigned q1 = cvt_pk_bf16(h0[2] - lo16f(p1), h0[3] - hi16f(p1));
        unsigned q2 = cvt_pk_bf16(h1[0] - lo16f(p2), h1[1] - hi16f(p2));
        unsigned q3 = cvt_pk_bf16(h1[2] - lo16f(p3), h1[3] - hi16f(p3));
        uint32x4 lop = {q0, q1, q2, q3};
        short8 Alo = bc8(lop);

        // ---- 4 gate-blocks x 4 MFMAs; all operands in named registers ----
        floatx4 d0 = __builtin_amdgcn_mfma_f32_16x16x32_bf16(A2, bc8(B2_0), zac, 0, 0, 0);
        d0 = __builtin_amdgcn_mfma_f32_16x16x32_bf16(Alo, bc8(BH_0), d0, 0, 0, 0);
        d0 = __builtin_amdgcn_mfma_f32_16x16x32_bf16(Ahi, bc8(BL_0), d0, 0, 0, 0);
        d0 = __builtin_amdgcn_mfma_f32_16x16x32_bf16(Ahi, bc8(BH_0), d0, 0, 0, 0);
        floatx4 d1 = __builtin_amdgcn_mfma_f32_16x16x32_bf16(A2, bc8(B2_1), zac, 0, 0, 0);
        d1 = __builtin_amdgcn_mfma_f32_16x16x32_bf16(Alo, bc8(BH_1), d1, 0, 0, 0);
        d1 = __builtin_amdgcn_mfma_f32_16x16x32_bf16(Ahi, bc8(BL_1), d1, 0, 0, 0);
        d1 = __builtin_amdgcn_mfma_f32_16x16x32_bf16(Ahi, bc8(BH_1), d1, 0, 0, 0);
        floatx4 d2 = __builtin_amdgcn_mfma_f32_16x16x32_bf16(A2, bc8(B2_2), zac, 0, 0, 0);
        d2 = __builtin_amdgcn_mfma_f32_16x16x32_bf16(Alo, bc8(BH_2), d2, 0, 0, 0);
        d2 = __builtin_amdgcn_mfma_f32_16x16x32_bf16(Ahi, bc8(BL_2), d2, 0, 0, 0);
        d2 = __builtin_amdgcn_mfma_f32_16x16x32_bf16(Ahi, bc8(BH_2), d2, 0, 0, 0);
        floatx4 d3 = __builtin_amdgcn_mfma_f32_16x16x32_bf16(A2, bc8(B2_3), zac, 0, 0, 0);
        d3 = __builtin_amdgcn_mfma_f32_16x16x32_bf16(Alo, bc8(BH_3), d3, 0, 0, 0);
        d3 = __builtin_amdgcn_mfma_f32_16x16x32_bf16(Ahi, bc8(BL_3), d3, 0, 0, 0);
        d3 = __builtin_amdgcn_mfma_f32_16x16x32_bf16(Ahi, bc8(BH_3), d3, 0, 0, 0);

        // ---- gates: d0=i, d1=f, d2=g, d3=o; per-q unrolled, named state ----
        {
            float ig, fg, gv, og;
            ig = sigf(d0[0]); fg = sigf(d1[0]); gv = tanhfast(d2[0]); og = sigf(d3[0]);
            cst0 = fg * cst0 + ig * gv; hn0 = og * tanhfast(cst0);
            ig = sigf(d0[1]); fg = sigf(d1[1]); gv = tanhfast(d2[1]); og = sigf(d3[1]);
            cst1 = fg * cst1 + ig * gv; hn1 = og * tanhfast(cst1);
            ig = sigf(d0[2]); fg = sigf(d1[2]); gv = tanhfast(d2[2]); og = sigf(d3[2]);
            cst2 = fg * cst2 + ig * gv; hn2 = og * tanhfast(cst2);
            ig = sigf(d0[3]); fg = sigf(d1[3]); gv = tanhfast(d2[3]); og = sigf(d3[3]);
            cst3 = fg * cst3 + ig * gv; hn3 = og * tanhfast(cst3);
        }

        // ---- h writeback to ping-pong buffer, then pair-visible barrier ----
        float* hw = &s_h[pair][t & 1][4 * grp][sub * 16 + col];
        hw[0 * 36] = hn0; hw[1 * 36] = hn1; hw[2 * 36] = hn2; hw[3 * 36] = hn3;
        __syncthreads();
    }

    {
        int node = node0 + 4 * grp;
        const int c = sub * 16 + col;
        if (node + 0 < N) t_out[(size_t)(node + 0) * LSTM_H + c] = hn0;
        if (node + 1 < N) t_out[(size_t)(node + 1) * LSTM_H + c] = hn1;
        if (node + 2 < N) t_out[(size_t)(node + 2) * LSTM_H + c] = hn2;
        if (node + 3 < N) t_out[(size_t)(node + 3) * LSTM_H + c] = hn3;
    }
}

// ---------- fusion MLP ----------
__global__ void fusion_kernel(const float* __restrict__ g2, const float* __restrict__ tt,
                              const float* __restrict__ Wf1, const float* __restrict__ bf1,
                              const float* __restrict__ Wf2, const float* __restrict__ bf2,
                              float* __restrict__ out, int N) {
    __shared__ float sW[96 * 64];
    __shared__ float sb1[64];
    __shared__ float sW2[128];
    for (int i = threadIdx.x; i < 96 * 64; i += 256) sW[i] = Wf1[i];
    if (threadIdx.x < 64) sb1[threadIdx.x] = bf1[threadIdx.x];
    if (threadIdx.x < 128) sW2[threadIdx.x] = Wf2[threadIdx.x];
    __syncthreads();
    const int wave = threadIdx.x >> 6;
    const int lane = threadIdx.x & 63;
    for (int n = blockIdx.x * 4 + wave; n < N; n += gridDim.x * 4) {
        const float* gn = g2 + (size_t)n * 64;
        const float* tn = tt + (size_t)n * 32;
        float acc = sb1[lane];
#pragma unroll 8
        for (int k = 0; k < 64; k++) acc += gn[k] * sW[k * 64 + lane];
#pragma unroll 8
        for (int k = 0; k < 32; k++) acc += tn[k] * sW[(64 + k) * 64 + lane];
        acc = fmaxf(acc, 0.0f);
        float o0 = acc * sW2[lane * 2 + 0];
        float o1 = acc * sW2[lane * 2 + 1];
#pragma unroll
        for (int mk = 32; mk >= 1; mk >>= 1) {
            o0 += __shfl_xor(o0, mk);
            o1 += __shfl_xor(o1, mk);
        }
        if (lane == 0) {
            out[(size_t)n * 2 + 0] = o0 + bf2[0];
            out[(size_t)n * 2 + 1] = o1 + bf2[1];
        }
    }
}

extern "C" void kernel_launch(void* const* d_in, const int* in_sizes, int n_in,
                              void* d_out, int out_size, void* d_ws, size_t ws_size,
                              hipStream_t stream) {
    const float* x      = (const float*)d_in[0];
    const int*   eidx   = (const int*)d_in[1];
    const float* seq    = (const float*)d_in[2];
    const float* W1     = (const float*)d_in[3];
    const float* att_s1 = (const float*)d_in[4];
    const float* att_d1 = (const float*)d_in[5];
    const float* bias1  = (const float*)d_in[6];
    const float* W2     = (const float*)d_in[7];
    const float* att_s2 = (const float*)d_in[8];
    const float* att_d2 = (const float*)d_in[9];
    const float* bias2  = (const float*)d_in[10];
    const float* Wih    = (const float*)d_in[11];
    const float* Whh    = (const float*)d_in[12];
    const float* bih    = (const float*)d_in[13];
    const float* bhh    = (const float*)d_in[14];
    const float* Wf1    = (const float*)d_in[15];
    const float* bf1    = (const float*)d_in[16];
    const float* Wf2    = (const float*)d_in[17];
    const float* bf2    = (const float*)d_in[18];
    float* out = (float*)d_out;

    const int N  = in_sizes[0] / IN_F;   // 50000
    const int E  = in_sizes[1] / 2;      // 800000
    const int ET = E + N;
    const int* srcs = eidx;
    const int* dsts = eidx + E;

    // workspace layout
    float* fws = (float*)d_ws;
    size_t o = 0;
    float* h1  = fws + o; o += (size_t)N * 256;
    float* g1  = fws + o; o += (size_t)N * 256;
    float* as1 = fws + o; o += (size_t)N * 4;
    float* ad1 = fws + o; o += (size_t)N * 4;
    int* cnt    = (int*)(fws + o);
    int* rowp   = cnt + N;
    int* cursor = rowp + N + 1;
    int* eid    = cursor + N;
    int* bsum   = eid + ET;
    // layer-2 / LSTM aliases (h1 region dead after layer-1 aggregation)
    float* h2 = h1;                      // N*64
    float* g2 = h1 + (size_t)N * 64;     // N*64
    float* tt = h1 + (size_t)N * 128;    // N*32
    float* as2 = as1; float* ad2 = ad1;

    const int nTiles = (N + 255) / 256;
    dim3 blk(256);

    // ---- CSR build ----
    hipMemsetAsync(cnt, 0, (size_t)N * sizeof(int), stream);
    hipMemsetAsync(cursor, 0, (size_t)N * sizeof(int), stream);
    count_deg<<<(ET + 255) / 256, blk, 0, stream>>>(dsts, E, ET, cnt);
    scan1<<<nTiles, blk, 0, stream>>>(cnt, rowp, bsum, N);
    scan2<<<1, blk, 0, stream>>>(bsum, nTiles);
    scan3<<<(N + 256) / 256, blk, 0, stream>>>(rowp, bsum, N, ET);
    scatter_edges<<<(ET + 255) / 256, blk, 0, stream>>>(dsts, E, ET, rowp, cursor, eid);

    // ---- GAT layer 1 ----
    gemm64<128, 256><<<dim3((N + 63) / 64, 4), blk, 0, stream>>>(x, W1, h1, N);
    att_scores<<<(N * 4 + 255) / 256, blk, 0, stream>>>(h1, att_s1, att_d1, as1, ad1, N * 4, 3);
    gat_agg4_sp<<<(N + 3) / 4, blk, 0, stream>>>(srcs, E, rowp, eid, as1, ad1, h1, bias1, g1, N);

    // ---- LSTM (MFMA; waves_per_eu(2,4) so allocator budgets 128 regs) ----
    lstm_mfma<<<(N + 63) / 64, dim3(512), 0, stream>>>(seq, Wih, Whh, bih, bhh, tt, N);

    // ---- GAT layer 2 ----
    gemm64<256, 64><<<dim3((N + 63) / 64, 1), blk, 0, stream>>>(g1, W2, h2, N);
    att_scores<<<(N + 255) / 256, blk, 0, stream>>>(h2, att_s2, att_d2, as2, ad2, N, 0);
    gat_agg1_sp<<<(N + 3) / 4, blk, 0, stream>>>(srcs, E, rowp, eid, as2, ad2, h2, bias2, g2, N);

    // ---- fusion MLP ----
    fusion_kernel<<<512, blk, 0, stream>>>(g2, tt, Wf1, bf1, Wf2, bf2, out, N);
}

// Round 8
// 769.971 us; speedup vs baseline: 1.1633x; 1.1397x over previous
//
#include <hip/hip_runtime.h>
#include <math.h>

#define HEADS1 4
#define HID 64
#define LSTM_H 32
#define IN_F 128
#define T_STEPS 50
#define NEG_SLOPE 0.2f
#define EPS_A 1e-16f

typedef __attribute__((ext_vector_type(8))) short short8;
typedef __attribute__((ext_vector_type(4))) float floatx4;
typedef __attribute__((ext_vector_type(4))) unsigned uint32x4;

// ---------- helpers ----------
// Single-instruction reciprocal (1 ulp). Without -ffast-math the compiler
// expands 1.0f/x to the ~12-inst IEEE div sequence; the LSTM gates do 20
// divisions per wave-timestep -> ~480 cycles of the measured ~1700. [r16]
__device__ __forceinline__ float frcp(float x) {
    float r;
    asm("v_rcp_f32 %0, %1" : "=v"(r) : "v"(x));
    return r;
}
__device__ __forceinline__ float sigf(float x) { return frcp(1.0f + __expf(-x)); }
__device__ __forceinline__ float tanhfast(float x) {
    float e = __expf(2.0f * x);
    return 1.0f - 2.0f * frcp(e + 1.0f);
}
__device__ __forceinline__ unsigned short f2bf(float f) {
    unsigned u = __float_as_uint(f);
    unsigned r = (u + 0x7FFFu + ((u >> 16) & 1u)) >> 16;
    return (unsigned short)r;
}
__device__ __forceinline__ float bf2f(unsigned short s) {
    return __uint_as_float(((unsigned)s) << 16);
}
// HW packed fp32->bf16 (2 values / instruction); no builtin on gfx950, inline asm.
__device__ __forceinline__ unsigned cvt_pk_bf16(float a, float b) {
    unsigned r;
    asm("v_cvt_pk_bf16_f32 %0, %1, %2" : "=v"(r) : "v"(a), "v"(b));
    return r;
}
__device__ __forceinline__ float lo16f(unsigned p) { return __uint_as_float(p << 16); }
__device__ __forceinline__ float hi16f(unsigned p) { return __uint_as_float(p & 0xffff0000u); }
__device__ __forceinline__ short8 bc8(uint32x4 v) { return __builtin_bit_cast(short8, v); }

// ---------- GEMM: C[M,NC] = A[M,K] @ B[K,NC]; 64x64 tile, 4x4 micro ----------
template <int K, int NC>
__global__ __launch_bounds__(256) void gemm64(const float* __restrict__ A,
                                              const float* __restrict__ B,
                                              float* __restrict__ C, int M) {
    constexpr int KC = 32;
    __shared__ float As[KC][68];
    __shared__ float Bs[KC][64];
    const int row0 = blockIdx.x * 64;
    const int col0 = blockIdx.y * 64;
    const int tx = threadIdx.x & 15;
    const int ty = threadIdx.x >> 4;
    float acc[4][4] = {{0.f}};

    for (int k0 = 0; k0 < K; k0 += KC) {
        {
            const int kk = threadIdx.x & 31;
            const int rb = threadIdx.x >> 5;
#pragma unroll
            for (int r = 0; r < 8; r++) {
                int row = row0 + rb + r * 8;
                As[kk][rb + r * 8] = (row < M) ? A[(size_t)row * K + k0 + kk] : 0.0f;
            }
            const int c  = threadIdx.x & 63;
            const int kb = threadIdx.x >> 6;
#pragma unroll
            for (int q = 0; q < KC / 4; q++)
                Bs[kb + q * 4][c] = B[(size_t)(k0 + kb + q * 4) * NC + col0 + c];
        }
        __syncthreads();
#pragma unroll
        for (int kk = 0; kk < KC; kk++) {
            float4 a4 = *(const float4*)&As[kk][ty * 4];
            float4 b4 = *(const float4*)&Bs[kk][tx * 4];
            float av[4] = {a4.x, a4.y, a4.z, a4.w};
            float bv[4] = {b4.x, b4.y, b4.z, b4.w};
#pragma unroll
            for (int i = 0; i < 4; i++)
#pragma unroll
                for (int j = 0; j < 4; j++) acc[i][j] += av[i] * bv[j];
        }
        __syncthreads();
    }
#pragma unroll
    for (int i = 0; i < 4; i++) {
        int row = row0 + ty * 4 + i;
        if (row < M) {
            float4 v = make_float4(acc[i][0], acc[i][1], acc[i][2], acc[i][3]);
            *(float4*)&C[(size_t)row * NC + col0 + tx * 4] = v;
        }
    }
}

// ---------- attention scores ----------
__global__ void att_scores(const float* __restrict__ h, const float* __restrict__ att_s,
                           const float* __restrict__ att_d, float* __restrict__ as_,
                           float* __restrict__ ad_, int NH, int Hmask) {
    int i = blockIdx.x * blockDim.x + threadIdx.x;
    if (i >= NH) return;
    int hh = i & Hmask;
    const float* row = h + (size_t)i * HID;
    float s = 0.0f, d = 0.0f;
#pragma unroll 8
    for (int c = 0; c < HID; c++) {
        float v = row[c];
        s += v * att_s[hh * HID + c];
        d += v * att_d[hh * HID + c];
    }
    as_[i] = s;
    ad_[i] = d;
}

// ---------- CSR build ----------
__global__ void count_deg(const int* __restrict__ dsts, int E, int ET, int* __restrict__ cnt) {
    int e = blockIdx.x * blockDim.x + threadIdx.x;
    if (e >= ET) return;
    int d = (e < E) ? dsts[e] : (e - E);
    atomicAdd(&cnt[d], 1);
}

__global__ void scan1(const int* __restrict__ cnt, int* __restrict__ rowp,
                      int* __restrict__ bsum, int N) {
    __shared__ int tmp[256];
    int i = blockIdx.x * 256 + threadIdx.x;
    int v = (i < N) ? cnt[i] : 0;
    tmp[threadIdx.x] = v;
    __syncthreads();
    for (int off = 1; off < 256; off <<= 1) {
        int t = (threadIdx.x >= (unsigned)off) ? tmp[threadIdx.x - off] : 0;
        __syncthreads();
        tmp[threadIdx.x] += t;
        __syncthreads();
    }
    if (i < N) rowp[i] = tmp[threadIdx.x] - v;
    if (threadIdx.x == 255) bsum[blockIdx.x] = tmp[255];
}

__global__ void scan2(int* __restrict__ bsum, int nb) {
    __shared__ int tmp[256];
    int v = (threadIdx.x < (unsigned)nb) ? bsum[threadIdx.x] : 0;
    tmp[threadIdx.x] = v;
    __syncthreads();
    for (int off = 1; off < 256; off <<= 1) {
        int t = (threadIdx.x >= (unsigned)off) ? tmp[threadIdx.x - off] : 0;
        __syncthreads();
        tmp[threadIdx.x] += t;
        __syncthreads();
    }
    if (threadIdx.x < (unsigned)nb) bsum[threadIdx.x] = tmp[threadIdx.x] - v;
}

__global__ void scan3(int* __restrict__ rowp, const int* __restrict__ bsum, int N, int ET) {
    int i = blockIdx.x * 256 + threadIdx.x;
    if (i < N) rowp[i] += bsum[blockIdx.x];
    if (i == 0) rowp[N] = ET;
}

__global__ void scatter_edges(const int* __restrict__ dsts, int E, int ET,
                              const int* __restrict__ rowp, int* __restrict__ cursor,
                              int* __restrict__ eid) {
    int e = blockIdx.x * blockDim.x + threadIdx.x;
    if (e >= ET) return;
    int d = (e < E) ? dsts[e] : (e - E);
    int pos = atomicAdd(&cursor[d], 1);
    eid[rowp[d] + pos] = e;
}

// ---------- GAT layer-1 aggregation: single pass, one wave per dst, 4 heads ----------
// Scores are O(1) => exp without segment-max is numerically identical.
__global__ __launch_bounds__(256)
void gat_agg4_sp(const int* __restrict__ srcs, int E,
                 const int* __restrict__ rowp, const int* __restrict__ eid,
                 const float* __restrict__ as_, const float* __restrict__ ad_,
                 const float* __restrict__ hfeat, const float* __restrict__ bias,
                 float* __restrict__ g, int N) {
    __shared__ float s_alpha[4][64][4];
    const int wave = threadIdx.x >> 6;
    const int lane = threadIdx.x & 63;
    const int head = lane >> 4;
    const int dst = blockIdx.x * 4 + wave;
    if (dst >= N) return;
    const int start = rowp[dst], end = rowp[dst + 1];
    const float4 adv = ((const float4*)ad_)[dst];
    const float4* h4 = (const float4*)hfeat;

    float4 dsum = make_float4(0.f, 0.f, 0.f, 0.f);
    float4 acc  = make_float4(0.f, 0.f, 0.f, 0.f);

    for (int i0 = start; i0 < end; i0 += 64) {
        int cnt = min(64, end - i0);
        int i = i0 + lane;
        int s = 0;
        if (i < end) {
            int e = eid[i];
            s = (e < E) ? srcs[e] : (e - E);
            float4 a = ((const float4*)as_)[s];
            float tx, ex;
            tx = a.x + adv.x; tx = (tx > 0.f) ? tx : NEG_SLOPE * tx; ex = __expf(tx);
            dsum.x += ex; s_alpha[wave][lane][0] = ex;
            tx = a.y + adv.y; tx = (tx > 0.f) ? tx : NEG_SLOPE * tx; ex = __expf(tx);
            dsum.y += ex; s_alpha[wave][lane][1] = ex;
            tx = a.z + adv.z; tx = (tx > 0.f) ? tx : NEG_SLOPE * tx; ex = __expf(tx);
            dsum.z += ex; s_alpha[wave][lane][2] = ex;
            tx = a.w + adv.w; tx = (tx > 0.f) ? tx : NEG_SLOPE * tx; ex = __expf(tx);
            dsum.w += ex; s_alpha[wave][lane][3] = ex;
        }
        __builtin_amdgcn_wave_barrier();
#pragma unroll 4
        for (int k = 0; k < cnt; k++) {
            float a_k = s_alpha[wave][k][head];   // 16-lane broadcast read
            int   s_k = __shfl(s, k);
            float4 hv = h4[(size_t)s_k * 64 + lane];
            acc.x += a_k * hv.x; acc.y += a_k * hv.y;
            acc.z += a_k * hv.z; acc.w += a_k * hv.w;
        }
        __builtin_amdgcn_wave_barrier();
    }
#pragma unroll
    for (int mk = 32; mk >= 1; mk >>= 1) {
        dsum.x += __shfl_xor(dsum.x, mk);
        dsum.y += __shfl_xor(dsum.y, mk);
        dsum.z += __shfl_xor(dsum.z, mk);
        dsum.w += __shfl_xor(dsum.w, mk);
    }
    float den = (head == 0) ? dsum.x : (head == 1) ? dsum.y : (head == 2) ? dsum.z : dsum.w;
    float inv = 1.0f / (den + EPS_A);
    float4 b4 = ((const float4*)bias)[lane];
    float4 r;
    r.x = acc.x * inv + b4.x; r.x = (r.x > 0.f) ? r.x : __expf(r.x) - 1.f;
    r.y = acc.y * inv + b4.y; r.y = (r.y > 0.f) ? r.y : __expf(r.y) - 1.f;
    r.z = acc.z * inv + b4.z; r.z = (r.z > 0.f) ? r.z : __expf(r.z) - 1.f;
    r.w = acc.w * inv + b4.w; r.w = (r.w > 0.f) ? r.w : __expf(r.w) - 1.f;
    ((float4*)g)[(size_t)dst * 64 + lane] = r;
}

// ---------- GAT layer-2 aggregation: single pass, one wave per dst, H=1 ----------
__global__ __launch_bounds__(256)
void gat_agg1_sp(const int* __restrict__ srcs, int E,
                 const int* __restrict__ rowp, const int* __restrict__ eid,
                 const float* __restrict__ as_, const float* __restrict__ ad_,
                 const float* __restrict__ hfeat, const float* __restrict__ bias,
                 float* __restrict__ g, int N) {
    __shared__ float s_alpha[4][64];
    const int wave = threadIdx.x >> 6;
    const int lane = threadIdx.x & 63;
    const int dst = blockIdx.x * 4 + wave;
    if (dst >= N) return;
    const int start = rowp[dst], end = rowp[dst + 1];
    const float adv = ad_[dst];

    float dsum = 0.0f, acc = 0.0f;
    for (int i0 = start; i0 < end; i0 += 64) {
        int cnt = min(64, end - i0);
        int i = i0 + lane;
        int s = 0;
        if (i < end) {
            int e = eid[i];
            s = (e < E) ? srcs[e] : (e - E);
            float t = as_[s] + adv;
            t = (t > 0.f) ? t : NEG_SLOPE * t;
            float ex = __expf(t);
            dsum += ex;
            s_alpha[wave][lane] = ex;
        }
        __builtin_amdgcn_wave_barrier();
#pragma unroll 4
        for (int k = 0; k < cnt; k++) {
            float a_k = s_alpha[wave][k];         // full-wave broadcast read
            int   s_k = __shfl(s, k);
            acc += a_k * hfeat[(size_t)s_k * 64 + lane];
        }
        __builtin_amdgcn_wave_barrier();
    }
#pragma unroll
    for (int mk = 32; mk >= 1; mk >>= 1) dsum += __shfl_xor(dsum, mk);
    g[(size_t)dst * 64 + lane] = acc / (dsum + EPS_A) + bias[lane];
}

// ---------- LSTM weight prepack (runs once, 1 block) ----------
// Writes the 12 per-lane MFMA B-fragments (B2/BH/BL x kk=0..3) pre-split into
// bf16 hi/lo and pre-packed 2-per-u32, indexed [kk][which][sub][lane] so a
// wave's 64 lanes load 16B each, coalesced. Removes ALL fragment-build
// arithmetic from the lstm loop: nothing left to rematerialize (r11-r15:
// allocator held 52 VGPR and rebuilt ~600 cyc/wave-ts of f2bf/pack in-loop).
__global__ void prep_wsplit(const float* __restrict__ Wih, const float* __restrict__ Whh,
                            const float* __restrict__ bih, const float* __restrict__ bhh,
                            uint32x4* __restrict__ wsp) {
    const int tid = threadIdx.x;          // 0..511
    const int kk = tid >> 7, sub = (tid >> 6) & 1, lane = tid & 63;
    const int grp = lane >> 4, col = lane & 15;
    const int krow = grp * 8;
    const int n = (sub + kk * 2) * 16 + col;
    float w[8];
    *(float4*)&w[0] = *(const float4*)&Whh[n * 32 + krow + 0];
    *(float4*)&w[4] = *(const float4*)&Whh[n * 32 + krow + 4];
    unsigned hi[8], lo[8];
#pragma unroll
    for (int j = 0; j < 8; j++) {
        unsigned short hs = f2bf(w[j]);
        hi[j] = hs;
        lo[j] = f2bf(w[j] - bf2f(hs));
    }
    uint32x4 BH = {hi[0] | (hi[1] << 16), hi[2] | (hi[3] << 16),
                   hi[4] | (hi[5] << 16), hi[6] | (hi[7] << 16)};
    uint32x4 BL = {lo[0] | (lo[1] << 16), lo[2] | (lo[3] << 16),
                   lo[4] | (lo[5] << 16), lo[6] | (lo[7] << 16)};
    float wi0 = Wih[n * 3 + 0], wi1 = Wih[n * 3 + 1], wi2 = Wih[n * 3 + 2];
    float bb = bih[n] + bhh[n];
    unsigned h0 = f2bf(wi0), h1 = f2bf(wi1), h2 = f2bf(wi2), hb = f2bf(bb);
    uint32x4 B2 = {0u, 0u, 0u, 0u};
    if (grp == 0) {
        unsigned bl_ = f2bf(bb - bf2f((unsigned short)hb));
        B2[0] = h0 | (h1 << 16); B2[1] = h2 | (hb << 16);
        B2[2] = h0 | (h1 << 16); B2[3] = h2 | (bl_ << 16);
    } else if (grp == 1) {
        unsigned l0 = f2bf(wi0 - bf2f((unsigned short)h0));
        unsigned l1 = f2bf(wi1 - bf2f((unsigned short)h1));
        unsigned l2 = f2bf(wi2 - bf2f((unsigned short)h2));
        B2[0] = l0 | (l1 << 16); B2[1] = l2;
    }
    wsp[((kk * 3 + 0) * 2 + sub) * 64 + lane] = B2;
    wsp[((kk * 3 + 1) * 2 + sub) * 64 + lane] = BH;
    wsp[((kk * 3 + 2) * 2 + sub) * 64 + lane] = BL;
}

// ---------- LSTM via MFMA (split-bf16), round-16 ----------
// Deltas vs round 15: (a) gate divisions use single-inst v_rcp_f32 (no
// -ffast-math in harness -> each 1/x was a ~12-inst IEEE sequence; 20 div
// per wave-ts = ~480 of the measured ~1700 VALU cycles); (b) weight
// fragments come pre-split/pre-packed from global (prep_wsplit) via 12
// coalesced dwordx4 loads -- the in-loop rebuild (~600 cyc/wave-ts across
// r11-r15, VGPR pinned at 52 by the allocator) has no arithmetic left to
// rematerialize; worst case is 12 L1-hit reloads (~50 cyc).
__global__ __launch_bounds__(512)
__attribute__((amdgpu_waves_per_eu(2, 4)))
void lstm_mfma(const float* __restrict__ seq, const uint32x4* __restrict__ wsp,
               float* __restrict__ t_out, int N) {
    __shared__ float s_seq[9600];           // [node 0..63][t*3+c], 38.4 KB
    __shared__ float s_h[4][2][16][36];     // [pair][pingpong][node][unit+pad] 18 KB

    const int tid  = threadIdx.x;
    const int wave = tid >> 6, lane = tid & 63;
    const int pair = wave >> 1, sub = wave & 1;
    const int grp  = lane >> 4, col = lane & 15;
    const int node0 = blockIdx.x * 64 + pair * 16;

    // ---- stage this block's seq slab (coalesced float4, zero-padded tail) ----
    {
        const size_t base  = (size_t)blockIdx.x * 9600;
        const size_t limit = (size_t)N * 150;
        for (int i = tid * 4; i < 9600; i += 512 * 4) {
            size_t g = base + i;
            float4 v;
            if (g + 3 < limit) {
                v = *(const float4*)&seq[g];
            } else {
                v.x = (g + 0 < limit) ? seq[g + 0] : 0.0f;
                v.y = (g + 1 < limit) ? seq[g + 1] : 0.0f;
                v.z = (g + 2 < limit) ? seq[g + 2] : 0.0f;
                v.w = (g + 3 < limit) ? seq[g + 3] : 0.0f;
            }
            *(float4*)&s_seq[i] = v;
        }
    }

    // ---- weight fragments: 12 coalesced 16B loads, no arithmetic ----
#define LF(KK, W) wsp[(((KK) * 3 + (W)) * 2 + sub) * 64 + lane]
    uint32x4 B2_0 = LF(0, 0), BH_0 = LF(0, 1), BL_0 = LF(0, 2);
    uint32x4 B2_1 = LF(1, 0), BH_1 = LF(1, 1), BL_1 = LF(1, 2);
    uint32x4 B2_2 = LF(2, 0), BH_2 = LF(2, 1), BL_2 = LF(2, 2);
    uint32x4 B2_3 = LF(3, 0), BH_3 = LF(3, 1), BL_3 = LF(3, 2);
#undef LF
    asm volatile("" : "+v"(B2_0), "+v"(BH_0), "+v"(BL_0),
                      "+v"(B2_1), "+v"(BH_1), "+v"(BL_1),
                      "+v"(B2_2), "+v"(BH_2), "+v"(BL_2),
                      "+v"(B2_3), "+v"(BH_3), "+v"(BL_3));

    for (int i = tid; i < 4 * 2 * 16 * 36; i += 512) ((float*)s_h)[i] = 0.0f;
    __syncthreads();

    float cst0 = 0.f, cst1 = 0.f, cst2 = 0.f, cst3 = 0.f;
    float hn0 = 0.f, hn1 = 0.f, hn2 = 0.f, hn3 = 0.f;
    const floatx4 zac = {0.f, 0.f, 0.f, 0.f};

    const bool g0 = (grp == 0);
    const float* xrow = &s_seq[(pair * 16 + col) * 150];

#pragma unroll 1
    for (int t = 0; t < T_STEPS; t++) {
        // ---- x from LDS (conflict-free; grp duplicates broadcast) ----
        float xv0 = xrow[t * 3 + 0];
        float xv1 = xrow[t * 3 + 1];
        float xv2 = xrow[t * 3 + 2];

        // ---- A2: x hi/lo + ones in K-slots (grp0: k'0-7, grp1: k'8-10) ----
        unsigned w0 = cvt_pk_bf16(xv0, xv1);
        unsigned w1 = cvt_pk_bf16(xv2, g0 ? 1.0f : 0.0f);
        float e0 = xv0 - lo16f(w0);
        float e1 = xv1 - hi16f(w0);
        float e2 = xv2 - lo16f(w1);
        unsigned w2 = g0 ? cvt_pk_bf16(e0, e1) : 0u;
        unsigned w3 = g0 ? cvt_pk_bf16(e2, 1.0f) : 0u;
        uint32x4 a2p = {w0, w1, w2, w3};
        short8 A2 = bc8(a2p);

        // ---- A (h) hi/lo from ping-pong LDS (prev buffer; t=0 reads zeros) ----
        const float* hr = &s_h[pair][(t + 1) & 1][col][grp * 8];
        floatx4 h0 = *(const floatx4*)&hr[0];
        floatx4 h1 = *(const floatx4*)&hr[4];
        unsigned p0 = cvt_pk_bf16(h0[0], h0[1]);
        unsigned p1 = cvt_pk_bf16(h0[2], h0[3]);
        unsigned p2 = cvt_pk_bf16(h1[0], h1[1]);
        unsigned p3 = cvt_pk_bf16(h1[2], h1[3]);
        uint32x4 hip = {p0, p1, p2, p3};
        short8 Ahi = bc8(hip);
        unsigned q0 = cvt_pk_bf16(h0[0] - lo16f(p0), h0[1] - hi16f(p0));
        unsigned q1 = cvt_pk_bf16(h0[2] - lo16f(p1), h0[3] - hi16f(p1));
        unsigned q2 = cvt_pk_bf16(h1[0] - lo16f(p2), h1[1] - hi16f(p2));
        unsigned q3 = cvt_pk_bf16(h1[2] - lo16f(p3), h1[3] - hi16f(p3));
        uint32x4 lop = {q0, q1, q2, q3};
        short8 Alo = bc8(lop);

        // ---- 4 gate-blocks x 4 MFMAs; all operands in registers ----
        floatx4 d0 = __builtin_amdgcn_mfma_f32_16x16x32_bf16(A2, bc8(B2_0), zac, 0, 0, 0);
        d0 = __builtin_amdgcn_mfma_f32_16x16x32_bf16(Alo, bc8(BH_0), d0, 0, 0, 0);
        d0 = __builtin_amdgcn_mfma_f32_16x16x32_bf16(Ahi, bc8(BL_0), d0, 0, 0, 0);
        d0 = __builtin_amdgcn_mfma_f32_16x16x32_bf16(Ahi, bc8(BH_0), d0, 0, 0, 0);
        floatx4 d1 = __builtin_amdgcn_mfma_f32_16x16x32_bf16(A2, bc8(B2_1), zac, 0, 0, 0);
        d1 = __builtin_amdgcn_mfma_f32_16x16x32_bf16(Alo, bc8(BH_1), d1, 0, 0, 0);
        d1 = __builtin_amdgcn_mfma_f32_16x16x32_bf16(Ahi, bc8(BL_1), d1, 0, 0, 0);
        d1 = __builtin_amdgcn_mfma_f32_16x16x32_bf16(Ahi, bc8(BH_1), d1, 0, 0, 0);
        floatx4 d2 = __builtin_amdgcn_mfma_f32_16x16x32_bf16(A2, bc8(B2_2), zac, 0, 0, 0);
        d2 = __builtin_amdgcn_mfma_f32_16x16x32_bf16(Alo, bc8(BH_2), d2, 0, 0, 0);
        d2 = __builtin_amdgcn_mfma_f32_16x16x32_bf16(Ahi, bc8(BL_2), d2, 0, 0, 0);
        d2 = __builtin_amdgcn_mfma_f32_16x16x32_bf16(Ahi, bc8(BH_2), d2, 0, 0, 0);
        floatx4 d3 = __builtin_amdgcn_mfma_f32_16x16x32_bf16(A2, bc8(B2_3), zac, 0, 0, 0);
        d3 = __builtin_amdgcn_mfma_f32_16x16x32_bf16(Alo, bc8(BH_3), d3, 0, 0, 0);
        d3 = __builtin_amdgcn_mfma_f32_16x16x32_bf16(Ahi, bc8(BL_3), d3, 0, 0, 0);
        d3 = __builtin_amdgcn_mfma_f32_16x16x32_bf16(Ahi, bc8(BH_3), d3, 0, 0, 0);

        // ---- gates: d0=i, d1=f, d2=g, d3=o; per-q unrolled, named state ----
        {
            float ig, fg, gv, og;
            ig = sigf(d0[0]); fg = sigf(d1[0]); gv = tanhfast(d2[0]); og = sigf(d3[0]);
            cst0 = fg * cst0 + ig * gv; hn0 = og * tanhfast(cst0);
            ig = sigf(d0[1]); fg = sigf(d1[1]); gv = tanhfast(d2[1]); og = sigf(d3[1]);
            cst1 = fg * cst1 + ig * gv; hn1 = og * tanhfast(cst1);
            ig = sigf(d0[2]); fg = sigf(d1[2]); gv = tanhfast(d2[2]); og = sigf(d3[2]);
            cst2 = fg * cst2 + ig * gv; hn2 = og * tanhfast(cst2);
            ig = sigf(d0[3]); fg = sigf(d1[3]); gv = tanhfast(d2[3]); og = sigf(d3[3]);
            cst3 = fg * cst3 + ig * gv; hn3 = og * tanhfast(cst3);
        }

        // ---- h writeback to ping-pong buffer, then pair-visible barrier ----
        float* hw = &s_h[pair][t & 1][4 * grp][sub * 16 + col];
        hw[0 * 36] = hn0; hw[1 * 36] = hn1; hw[2 * 36] = hn2; hw[3 * 36] = hn3;
        __syncthreads();
    }

    {
        int node = node0 + 4 * grp;
        const int c = sub * 16 + col;
        if (node + 0 < N) t_out[(size_t)(node + 0) * LSTM_H + c] = hn0;
        if (node + 1 < N) t_out[(size_t)(node + 1) * LSTM_H + c] = hn1;
        if (node + 2 < N) t_out[(size_t)(node + 2) * LSTM_H + c] = hn2;
        if (node + 3 < N) t_out[(size_t)(node + 3) * LSTM_H + c] = hn3;
    }
}

// ---------- fusion MLP ----------
__global__ void fusion_kernel(const float* __restrict__ g2, const float* __restrict__ tt,
                              const float* __restrict__ Wf1, const float* __restrict__ bf1,
                              const float* __restrict__ Wf2, const float* __restrict__ bf2,
                              float* __restrict__ out, int N) {
    __shared__ float sW[96 * 64];
    __shared__ float sb1[64];
    __shared__ float sW2[128];
    for (int i = threadIdx.x; i < 96 * 64; i += 256) sW[i] = Wf1[i];
    if (threadIdx.x < 64) sb1[threadIdx.x] = bf1[threadIdx.x];
    if (threadIdx.x < 128) sW2[threadIdx.x] = Wf2[threadIdx.x];
    __syncthreads();
    const int wave = threadIdx.x >> 6;
    const int lane = threadIdx.x & 63;
    for (int n = blockIdx.x * 4 + wave; n < N; n += gridDim.x * 4) {
        const float* gn = g2 + (size_t)n * 64;
        const float* tn = tt + (size_t)n * 32;
        float acc = sb1[lane];
#pragma unroll 8
        for (int k = 0; k < 64; k++) acc += gn[k] * sW[k * 64 + lane];
#pragma unroll 8
        for (int k = 0; k < 32; k++) acc += tn[k] * sW[(64 + k) * 64 + lane];
        acc = fmaxf(acc, 0.0f);
        float o0 = acc * sW2[lane * 2 + 0];
        float o1 = acc * sW2[lane * 2 + 1];
#pragma unroll
        for (int mk = 32; mk >= 1; mk >>= 1) {
            o0 += __shfl_xor(o0, mk);
            o1 += __shfl_xor(o1, mk);
        }
        if (lane == 0) {
            out[(size_t)n * 2 + 0] = o0 + bf2[0];
            out[(size_t)n * 2 + 1] = o1 + bf2[1];
        }
    }
}

extern "C" void kernel_launch(void* const* d_in, const int* in_sizes, int n_in,
                              void* d_out, int out_size, void* d_ws, size_t ws_size,
                              hipStream_t stream) {
    const float* x      = (const float*)d_in[0];
    const int*   eidx   = (const int*)d_in[1];
    const float* seq    = (const float*)d_in[2];
    const float* W1     = (const float*)d_in[3];
    const float* att_s1 = (const float*)d_in[4];
    const float* att_d1 = (const float*)d_in[5];
    const float* bias1  = (const float*)d_in[6];
    const float* W2     = (const float*)d_in[7];
    const float* att_s2 = (const float*)d_in[8];
    const float* att_d2 = (const float*)d_in[9];
    const float* bias2  = (const float*)d_in[10];
    const float* Wih    = (const float*)d_in[11];
    const float* Whh    = (const float*)d_in[12];
    const float* bih    = (const float*)d_in[13];
    const float* bhh    = (const float*)d_in[14];
    const float* Wf1    = (const float*)d_in[15];
    const float* bf1    = (const float*)d_in[16];
    const float* Wf2    = (const float*)d_in[17];
    const float* bf2    = (const float*)d_in[18];
    float* out = (float*)d_out;

    const int N  = in_sizes[0] / IN_F;   // 50000
    const int E  = in_sizes[1] / 2;      // 800000
    const int ET = E + N;
    const int* srcs = eidx;
    const int* dsts = eidx + E;

    // workspace layout
    float* fws = (float*)d_ws;
    size_t o = 0;
    float* h1  = fws + o; o += (size_t)N * 256;
    float* g1  = fws + o; o += (size_t)N * 256;
    float* as1 = fws + o; o += (size_t)N * 4;
    float* ad1 = fws + o; o += (size_t)N * 4;
    int* cnt    = (int*)(fws + o);
    int* rowp   = cnt + N;
    int* cursor = rowp + N + 1;
    int* eid    = cursor + N;
    int* bsum   = eid + ET;
    // prepacked LSTM weight fragments (24.5 KB, 16B-aligned)
    uintptr_t wp_ = (uintptr_t)(bsum + 512);
    wp_ = (wp_ + 15) & ~(uintptr_t)15;
    uint32x4* wsp = (uint32x4*)wp_;
    // layer-2 / LSTM aliases (h1 region dead after layer-1 aggregation)
    float* h2 = h1;                      // N*64
    float* g2 = h1 + (size_t)N * 64;     // N*64
    float* tt = h1 + (size_t)N * 128;    // N*32
    float* as2 = as1; float* ad2 = ad1;

    const int nTiles = (N + 255) / 256;
    dim3 blk(256);

    // ---- CSR build ----
    hipMemsetAsync(cnt, 0, (size_t)N * sizeof(int), stream);
    hipMemsetAsync(cursor, 0, (size_t)N * sizeof(int), stream);
    count_deg<<<(ET + 255) / 256, blk, 0, stream>>>(dsts, E, ET, cnt);
    scan1<<<nTiles, blk, 0, stream>>>(cnt, rowp, bsum, N);
    scan2<<<1, blk, 0, stream>>>(bsum, nTiles);
    scan3<<<(N + 256) / 256, blk, 0, stream>>>(rowp, bsum, N, ET);
    scatter_edges<<<(ET + 255) / 256, blk, 0, stream>>>(dsts, E, ET, rowp, cursor, eid);

    // ---- LSTM weight prepack (tiny, once) ----
    prep_wsplit<<<1, 512, 0, stream>>>(Wih, Whh, bih, bhh, wsp);

    // ---- GAT layer 1 ----
    gemm64<128, 256><<<dim3((N + 63) / 64, 4), blk, 0, stream>>>(x, W1, h1, N);
    att_scores<<<(N * 4 + 255) / 256, blk, 0, stream>>>(h1, att_s1, att_d1, as1, ad1, N * 4, 3);
    gat_agg4_sp<<<(N + 3) / 4, blk, 0, stream>>>(srcs, E, rowp, eid, as1, ad1, h1, bias1, g1, N);

    // ---- LSTM (MFMA; prepacked weights, v_rcp gates, VMEM-free t-loop) ----
    lstm_mfma<<<(N + 63) / 64, dim3(512), 0, stream>>>(seq, wsp, tt, N);

    // ---- GAT layer 2 ----
    gemm64<256, 64><<<dim3((N + 63) / 64, 1), blk, 0, stream>>>(g1, W2, h2, N);
    att_scores<<<(N + 255) / 256, blk, 0, stream>>>(h2, att_s2, att_d2, as2, ad2, N, 0);
    gat_agg1_sp<<<(N + 3) / 4, blk, 0, stream>>>(srcs, E, rowp, eid, as2, ad2, h2, bias2, g2, N);

    // ---- fusion MLP ----
    fusion_kernel<<<512, blk, 0, stream>>>(g2, tt, Wf1, bf1, Wf2, bf2, out, N);
}

// Round 9
// 731.390 us; speedup vs baseline: 1.2247x; 1.0528x over previous
//
#include <hip/hip_runtime.h>
#include <math.h>

#define HEADS1 4
#define HID 64
#define LSTM_H 32
#define IN_F 128
#define T_STEPS 50
#define NEG_SLOPE 0.2f
#define EPS_A 1e-16f

typedef __attribute__((ext_vector_type(8))) short short8;
typedef __attribute__((ext_vector_type(4))) float floatx4;
typedef __attribute__((ext_vector_type(4))) unsigned uint32x4;

// ---------- helpers ----------
// Single-instruction reciprocal (1 ulp). Without -ffast-math the compiler
// expands 1.0f/x to the ~12-inst IEEE div sequence. [r16: -42% on lstm]
__device__ __forceinline__ float frcp(float x) {
    float r;
    asm("v_rcp_f32 %0, %1" : "=v"(r) : "v"(x));
    return r;
}
__device__ __forceinline__ float sigf(float x) { return frcp(1.0f + __expf(-x)); }
__device__ __forceinline__ float tanhfast(float x) {
    float e = __expf(2.0f * x);
    return 1.0f - 2.0f * frcp(e + 1.0f);
}
__device__ __forceinline__ unsigned short f2bf(float f) {
    unsigned u = __float_as_uint(f);
    unsigned r = (u + 0x7FFFu + ((u >> 16) & 1u)) >> 16;
    return (unsigned short)r;
}
__device__ __forceinline__ float bf2f(unsigned short s) {
    return __uint_as_float(((unsigned)s) << 16);
}
// HW packed fp32->bf16 (2 values / instruction); no builtin on gfx950, inline asm.
__device__ __forceinline__ unsigned cvt_pk_bf16(float a, float b) {
    unsigned r;
    asm("v_cvt_pk_bf16_f32 %0, %1, %2" : "=v"(r) : "v"(a), "v"(b));
    return r;
}
__device__ __forceinline__ float lo16f(unsigned p) { return __uint_as_float(p << 16); }
__device__ __forceinline__ float hi16f(unsigned p) { return __uint_as_float(p & 0xffff0000u); }
__device__ __forceinline__ short8 bc8(uint32x4 v) { return __builtin_bit_cast(short8, v); }

// ---------- weight transpose+split prepack for MFMA GEMM ----------
// W [K][NC] fp32 -> Bt_hi/Bt_lo [NC][K] bf16 (split), so GEMM B-staging is
// coalesced short8 loads with zero conversion arithmetic in the GEMM loop.
template <int KK>
__global__ void prep_wt(const float* __restrict__ W, unsigned short* __restrict__ th,
                        unsigned short* __restrict__ tl, int total, int NC) {
    int i = blockIdx.x * 256 + threadIdx.x;
    if (i >= total) return;
    int n = i / KK, k = i - n * KK;
    float v = W[k * NC + n];
    unsigned short h = f2bf(v);
    th[i] = h;
    tl[i] = f2bf(v - bf2f(h));
}

// ---------- MFMA GEMM: C[M,NC] = A[M,K] @ B[K,NC], split-bf16 3-product ----
// Block: 256 thr (4 waves, 2x2), tile 128x64, K-step 32. A staged fp32 in LDS
// (pad 44: 2-way banks = free) and converted to hi/lo fragments in-register;
// B fragments read directly from prepacked transposed hi/lo LDS tiles.
// C ~= Ahi*Bhi + Ahi*Blo + Alo*Bhi (Alo*Blo ~ 2^-17 rel, dropped). Replaces
// the fp32-VALU gemm64 (2048 FMA + 256 ds_read_b128 per thread).
template <int K, int NC>
__global__ __launch_bounds__(256)
void gemm_mfma(const float* __restrict__ A, const unsigned short* __restrict__ Bth,
               const unsigned short* __restrict__ Btl, float* __restrict__ C, int M) {
    __shared__ float sA[128][44];            // 22.5 KB
    __shared__ unsigned short sBh[64][40];   // 5 KB
    __shared__ unsigned short sBl[64][40];   // 5 KB
    const int tid = threadIdx.x;
    const int wave = tid >> 6, lane = tid & 63;
    const int wr = wave >> 1, wc = wave & 1;
    const int row0 = blockIdx.x * 128;
    const int col0 = blockIdx.y * 64;
    const int l15 = lane & 15, l4 = lane >> 4;

    floatx4 acc[4][2];
#pragma unroll
    for (int rb = 0; rb < 4; rb++)
#pragma unroll
        for (int cb = 0; cb < 2; cb++) acc[rb][cb] = (floatx4){0.f, 0.f, 0.f, 0.f};

    for (int k0 = 0; k0 < K; k0 += 32) {
        __syncthreads();
        // ---- stage A fp32 tile [128][32] (coalesced 128B-per-8-thread rows) ----
#pragma unroll
        for (int q = 0; q < 4; q++) {
            int idx = q * 256 + tid;
            int row = idx >> 3, seg = idx & 7;
            int gr = row0 + row;
            float4 v = (gr < M) ? *(const float4*)&A[(size_t)gr * K + k0 + seg * 4]
                                : make_float4(0.f, 0.f, 0.f, 0.f);
            *(float4*)&sA[row][seg * 4] = v;
        }
        // ---- stage B hi/lo tiles [64][32] from transposed prepack ----
        {
            int col = tid >> 2, seg = tid & 3;
            size_t gb = (size_t)(col0 + col) * K + k0 + seg * 8;
            *(short8*)&sBh[col][seg * 8] = *(const short8*)&Bth[gb];
            *(short8*)&sBl[col][seg * 8] = *(const short8*)&Btl[gb];
        }
        __syncthreads();

        // ---- B fragments (col = lane&15, k = (lane>>4)*8+j) ----
        short8 bh0 = *(const short8*)&sBh[wc * 32 + 0 + l15][l4 * 8];
        short8 bl0 = *(const short8*)&sBl[wc * 32 + 0 + l15][l4 * 8];
        short8 bh1 = *(const short8*)&sBh[wc * 32 + 16 + l15][l4 * 8];
        short8 bl1 = *(const short8*)&sBl[wc * 32 + 16 + l15][l4 * 8];

#pragma unroll
        for (int rb = 0; rb < 4; rb++) {
            int row = wr * 64 + rb * 16 + l15;
            floatx4 a0 = *(const floatx4*)&sA[row][l4 * 8 + 0];
            floatx4 a1 = *(const floatx4*)&sA[row][l4 * 8 + 4];
            unsigned p0 = cvt_pk_bf16(a0[0], a0[1]);
            unsigned p1 = cvt_pk_bf16(a0[2], a0[3]);
            unsigned p2 = cvt_pk_bf16(a1[0], a1[1]);
            unsigned p3 = cvt_pk_bf16(a1[2], a1[3]);
            uint32x4 hp = {p0, p1, p2, p3};
            short8 Ah = bc8(hp);
            unsigned q0 = cvt_pk_bf16(a0[0] - lo16f(p0), a0[1] - hi16f(p0));
            unsigned q1 = cvt_pk_bf16(a0[2] - lo16f(p1), a0[3] - hi16f(p1));
            unsigned q2 = cvt_pk_bf16(a1[0] - lo16f(p2), a1[1] - hi16f(p2));
            unsigned q3 = cvt_pk_bf16(a1[2] - lo16f(p3), a1[3] - hi16f(p3));
            uint32x4 lp = {q0, q1, q2, q3};
            short8 Al = bc8(lp);

            acc[rb][0] = __builtin_amdgcn_mfma_f32_16x16x32_bf16(Ah, bh0, acc[rb][0], 0, 0, 0);
            acc[rb][0] = __builtin_amdgcn_mfma_f32_16x16x32_bf16(Ah, bl0, acc[rb][0], 0, 0, 0);
            acc[rb][0] = __builtin_amdgcn_mfma_f32_16x16x32_bf16(Al, bh0, acc[rb][0], 0, 0, 0);
            acc[rb][1] = __builtin_amdgcn_mfma_f32_16x16x32_bf16(Ah, bh1, acc[rb][1], 0, 0, 0);
            acc[rb][1] = __builtin_amdgcn_mfma_f32_16x16x32_bf16(Ah, bl1, acc[rb][1], 0, 0, 0);
            acc[rb][1] = __builtin_amdgcn_mfma_f32_16x16x32_bf16(Al, bh1, acc[rb][1], 0, 0, 0);
        }
    }

    // ---- epilogue: D row = (lane>>4)*4+q, col = lane&15 ----
#pragma unroll
    for (int rb = 0; rb < 4; rb++)
#pragma unroll
        for (int cb = 0; cb < 2; cb++)
#pragma unroll
            for (int q = 0; q < 4; q++) {
                int row = row0 + wr * 64 + rb * 16 + l4 * 4 + q;
                int col = col0 + wc * 32 + cb * 16 + l15;
                if (row < M) C[(size_t)row * NC + col] = acc[rb][cb][q];
            }
}

// ---------- attention scores ----------
__global__ void att_scores(const float* __restrict__ h, const float* __restrict__ att_s,
                           const float* __restrict__ att_d, float* __restrict__ as_,
                           float* __restrict__ ad_, int NH, int Hmask) {
    int i = blockIdx.x * blockDim.x + threadIdx.x;
    if (i >= NH) return;
    int hh = i & Hmask;
    const float* row = h + (size_t)i * HID;
    float s = 0.0f, d = 0.0f;
#pragma unroll 8
    for (int c = 0; c < HID; c++) {
        float v = row[c];
        s += v * att_s[hh * HID + c];
        d += v * att_d[hh * HID + c];
    }
    as_[i] = s;
    ad_[i] = d;
}

// ---------- CSR build ----------
__global__ void count_deg(const int* __restrict__ dsts, int E, int ET, int* __restrict__ cnt) {
    int e = blockIdx.x * blockDim.x + threadIdx.x;
    if (e >= ET) return;
    int d = (e < E) ? dsts[e] : (e - E);
    atomicAdd(&cnt[d], 1);
}

__global__ void scan1(const int* __restrict__ cnt, int* __restrict__ rowp,
                      int* __restrict__ bsum, int N) {
    __shared__ int tmp[256];
    int i = blockIdx.x * 256 + threadIdx.x;
    int v = (i < N) ? cnt[i] : 0;
    tmp[threadIdx.x] = v;
    __syncthreads();
    for (int off = 1; off < 256; off <<= 1) {
        int t = (threadIdx.x >= (unsigned)off) ? tmp[threadIdx.x - off] : 0;
        __syncthreads();
        tmp[threadIdx.x] += t;
        __syncthreads();
    }
    if (i < N) rowp[i] = tmp[threadIdx.x] - v;
    if (threadIdx.x == 255) bsum[blockIdx.x] = tmp[255];
}

__global__ void scan2(int* __restrict__ bsum, int nb) {
    __shared__ int tmp[256];
    int v = (threadIdx.x < (unsigned)nb) ? bsum[threadIdx.x] : 0;
    tmp[threadIdx.x] = v;
    __syncthreads();
    for (int off = 1; off < 256; off <<= 1) {
        int t = (threadIdx.x >= (unsigned)off) ? tmp[threadIdx.x - off] : 0;
        __syncthreads();
        tmp[threadIdx.x] += t;
        __syncthreads();
    }
    if (threadIdx.x < (unsigned)nb) bsum[threadIdx.x] = tmp[threadIdx.x] - v;
}

__global__ void scan3(int* __restrict__ rowp, const int* __restrict__ bsum, int N, int ET) {
    int i = blockIdx.x * 256 + threadIdx.x;
    if (i < N) rowp[i] += bsum[blockIdx.x];
    if (i == 0) rowp[N] = ET;
}

__global__ void scatter_edges(const int* __restrict__ dsts, int E, int ET,
                              const int* __restrict__ rowp, int* __restrict__ cursor,
                              int* __restrict__ eid) {
    int e = blockIdx.x * blockDim.x + threadIdx.x;
    if (e >= ET) return;
    int d = (e < E) ? dsts[e] : (e - E);
    int pos = atomicAdd(&cursor[d], 1);
    eid[rowp[d] + pos] = e;
}

// ---------- GAT layer-1 aggregation: single pass, one wave per dst, 4 heads ----------
// Scores are O(1) => exp without segment-max is numerically identical.
__global__ __launch_bounds__(256)
void gat_agg4_sp(const int* __restrict__ srcs, int E,
                 const int* __restrict__ rowp, const int* __restrict__ eid,
                 const float* __restrict__ as_, const float* __restrict__ ad_,
                 const float* __restrict__ hfeat, const float* __restrict__ bias,
                 float* __restrict__ g, int N) {
    __shared__ float s_alpha[4][64][4];
    const int wave = threadIdx.x >> 6;
    const int lane = threadIdx.x & 63;
    const int head = lane >> 4;
    const int dst = blockIdx.x * 4 + wave;
    if (dst >= N) return;
    const int start = rowp[dst], end = rowp[dst + 1];
    const float4 adv = ((const float4*)ad_)[dst];
    const float4* h4 = (const float4*)hfeat;

    float4 dsum = make_float4(0.f, 0.f, 0.f, 0.f);
    float4 acc  = make_float4(0.f, 0.f, 0.f, 0.f);

    for (int i0 = start; i0 < end; i0 += 64) {
        int cnt = min(64, end - i0);
        int i = i0 + lane;
        int s = 0;
        if (i < end) {
            int e = eid[i];
            s = (e < E) ? srcs[e] : (e - E);
            float4 a = ((const float4*)as_)[s];
            float tx, ex;
            tx = a.x + adv.x; tx = (tx > 0.f) ? tx : NEG_SLOPE * tx; ex = __expf(tx);
            dsum.x += ex; s_alpha[wave][lane][0] = ex;
            tx = a.y + adv.y; tx = (tx > 0.f) ? tx : NEG_SLOPE * tx; ex = __expf(tx);
            dsum.y += ex; s_alpha[wave][lane][1] = ex;
            tx = a.z + adv.z; tx = (tx > 0.f) ? tx : NEG_SLOPE * tx; ex = __expf(tx);
            dsum.z += ex; s_alpha[wave][lane][2] = ex;
            tx = a.w + adv.w; tx = (tx > 0.f) ? tx : NEG_SLOPE * tx; ex = __expf(tx);
            dsum.w += ex; s_alpha[wave][lane][3] = ex;
        }
        __builtin_amdgcn_wave_barrier();
#pragma unroll 4
        for (int k = 0; k < cnt; k++) {
            float a_k = s_alpha[wave][k][head];   // 16-lane broadcast read
            int   s_k = __shfl(s, k);
            float4 hv = h4[(size_t)s_k * 64 + lane];
            acc.x += a_k * hv.x; acc.y += a_k * hv.y;
            acc.z += a_k * hv.z; acc.w += a_k * hv.w;
        }
        __builtin_amdgcn_wave_barrier();
    }
#pragma unroll
    for (int mk = 32; mk >= 1; mk >>= 1) {
        dsum.x += __shfl_xor(dsum.x, mk);
        dsum.y += __shfl_xor(dsum.y, mk);
        dsum.z += __shfl_xor(dsum.z, mk);
        dsum.w += __shfl_xor(dsum.w, mk);
    }
    float den = (head == 0) ? dsum.x : (head == 1) ? dsum.y : (head == 2) ? dsum.z : dsum.w;
    float inv = 1.0f / (den + EPS_A);
    float4 b4 = ((const float4*)bias)[lane];
    float4 r;
    r.x = acc.x * inv + b4.x; r.x = (r.x > 0.f) ? r.x : __expf(r.x) - 1.f;
    r.y = acc.y * inv + b4.y; r.y = (r.y > 0.f) ? r.y : __expf(r.y) - 1.f;
    r.z = acc.z * inv + b4.z; r.z = (r.z > 0.f) ? r.z : __expf(r.z) - 1.f;
    r.w = acc.w * inv + b4.w; r.w = (r.w > 0.f) ? r.w : __expf(r.w) - 1.f;
    ((float4*)g)[(size_t)dst * 64 + lane] = r;
}

// ---------- GAT layer-2 aggregation: single pass, one wave per dst, H=1 ----------
__global__ __launch_bounds__(256)
void gat_agg1_sp(const int* __restrict__ srcs, int E,
                 const int* __restrict__ rowp, const int* __restrict__ eid,
                 const float* __restrict__ as_, const float* __restrict__ ad_,
                 const float* __restrict__ hfeat, const float* __restrict__ bias,
                 float* __restrict__ g, int N) {
    __shared__ float s_alpha[4][64];
    const int wave = threadIdx.x >> 6;
    const int lane = threadIdx.x & 63;
    const int dst = blockIdx.x * 4 + wave;
    if (dst >= N) return;
    const int start = rowp[dst], end = rowp[dst + 1];
    const float adv = ad_[dst];

    float dsum = 0.0f, acc = 0.0f;
    for (int i0 = start; i0 < end; i0 += 64) {
        int cnt = min(64, end - i0);
        int i = i0 + lane;
        int s = 0;
        if (i < end) {
            int e = eid[i];
            s = (e < E) ? srcs[e] : (e - E);
            float t = as_[s] + adv;
            t = (t > 0.f) ? t : NEG_SLOPE * t;
            float ex = __expf(t);
            dsum += ex;
            s_alpha[wave][lane] = ex;
        }
        __builtin_amdgcn_wave_barrier();
#pragma unroll 4
        for (int k = 0; k < cnt; k++) {
            float a_k = s_alpha[wave][k];         // full-wave broadcast read
            int   s_k = __shfl(s, k);
            acc += a_k * hfeat[(size_t)s_k * 64 + lane];
        }
        __builtin_amdgcn_wave_barrier();
    }
#pragma unroll
    for (int mk = 32; mk >= 1; mk >>= 1) dsum += __shfl_xor(dsum, mk);
    g[(size_t)dst * 64 + lane] = acc / (dsum + EPS_A) + bias[lane];
}

// ---------- LSTM weight prepack (runs once, 1 block) ----------
__global__ void prep_wsplit(const float* __restrict__ Wih, const float* __restrict__ Whh,
                            const float* __restrict__ bih, const float* __restrict__ bhh,
                            uint32x4* __restrict__ wsp) {
    const int tid = threadIdx.x;          // 0..511
    const int kk = tid >> 7, sub = (tid >> 6) & 1, lane = tid & 63;
    const int grp = lane >> 4, col = lane & 15;
    const int krow = grp * 8;
    const int n = (sub + kk * 2) * 16 + col;
    float w[8];
    *(float4*)&w[0] = *(const float4*)&Whh[n * 32 + krow + 0];
    *(float4*)&w[4] = *(const float4*)&Whh[n * 32 + krow + 4];
    unsigned hi[8], lo[8];
#pragma unroll
    for (int j = 0; j < 8; j++) {
        unsigned short hs = f2bf(w[j]);
        hi[j] = hs;
        lo[j] = f2bf(w[j] - bf2f(hs));
    }
    uint32x4 BH = {hi[0] | (hi[1] << 16), hi[2] | (hi[3] << 16),
                   hi[4] | (hi[5] << 16), hi[6] | (hi[7] << 16)};
    uint32x4 BL = {lo[0] | (lo[1] << 16), lo[2] | (lo[3] << 16),
                   lo[4] | (lo[5] << 16), lo[6] | (lo[7] << 16)};
    float wi0 = Wih[n * 3 + 0], wi1 = Wih[n * 3 + 1], wi2 = Wih[n * 3 + 2];
    float bb = bih[n] + bhh[n];
    unsigned h0 = f2bf(wi0), h1 = f2bf(wi1), h2 = f2bf(wi2), hb = f2bf(bb);
    uint32x4 B2 = {0u, 0u, 0u, 0u};
    if (grp == 0) {
        unsigned bl_ = f2bf(bb - bf2f((unsigned short)hb));
        B2[0] = h0 | (h1 << 16); B2[1] = h2 | (hb << 16);
        B2[2] = h0 | (h1 << 16); B2[3] = h2 | (bl_ << 16);
    } else if (grp == 1) {
        unsigned l0 = f2bf(wi0 - bf2f((unsigned short)h0));
        unsigned l1 = f2bf(wi1 - bf2f((unsigned short)h1));
        unsigned l2 = f2bf(wi2 - bf2f((unsigned short)h2));
        B2[0] = l0 | (l1 << 16); B2[1] = l2;
    }
    wsp[((kk * 3 + 0) * 2 + sub) * 64 + lane] = B2;
    wsp[((kk * 3 + 1) * 2 + sub) * 64 + lane] = BH;
    wsp[((kk * 3 + 2) * 2 + sub) * 64 + lane] = BL;
}

// ---------- LSTM via MFMA (split-bf16), round-16 structure (unchanged) ----------
__global__ __launch_bounds__(512)
__attribute__((amdgpu_waves_per_eu(2, 4)))
void lstm_mfma(const float* __restrict__ seq, const uint32x4* __restrict__ wsp,
               float* __restrict__ t_out, int N) {
    __shared__ float s_seq[9600];           // [node 0..63][t*3+c], 38.4 KB
    __shared__ float s_h[4][2][16][36];     // [pair][pingpong][node][unit+pad] 18 KB

    const int tid  = threadIdx.x;
    const int wave = tid >> 6, lane = tid & 63;
    const int pair = wave >> 1, sub = wave & 1;
    const int grp  = lane >> 4, col = lane & 15;
    const int node0 = blockIdx.x * 64 + pair * 16;

    {
        const size_t base  = (size_t)blockIdx.x * 9600;
        const size_t limit = (size_t)N * 150;
        for (int i = tid * 4; i < 9600; i += 512 * 4) {
            size_t g = base + i;
            float4 v;
            if (g + 3 < limit) {
                v = *(const float4*)&seq[g];
            } else {
                v.x = (g + 0 < limit) ? seq[g + 0] : 0.0f;
                v.y = (g + 1 < limit) ? seq[g + 1] : 0.0f;
                v.z = (g + 2 < limit) ? seq[g + 2] : 0.0f;
                v.w = (g + 3 < limit) ? seq[g + 3] : 0.0f;
            }
            *(float4*)&s_seq[i] = v;
        }
    }

#define LF(KK, W) wsp[(((KK) * 3 + (W)) * 2 + sub) * 64 + lane]
    uint32x4 B2_0 = LF(0, 0), BH_0 = LF(0, 1), BL_0 = LF(0, 2);
    uint32x4 B2_1 = LF(1, 0), BH_1 = LF(1, 1), BL_1 = LF(1, 2);
    uint32x4 B2_2 = LF(2, 0), BH_2 = LF(2, 1), BL_2 = LF(2, 2);
    uint32x4 B2_3 = LF(3, 0), BH_3 = LF(3, 1), BL_3 = LF(3, 2);
#undef LF
    asm volatile("" : "+v"(B2_0), "+v"(BH_0), "+v"(BL_0),
                      "+v"(B2_1), "+v"(BH_1), "+v"(BL_1),
                      "+v"(B2_2), "+v"(BH_2), "+v"(BL_2),
                      "+v"(B2_3), "+v"(BH_3), "+v"(BL_3));

    for (int i = tid; i < 4 * 2 * 16 * 36; i += 512) ((float*)s_h)[i] = 0.0f;
    __syncthreads();

    float cst0 = 0.f, cst1 = 0.f, cst2 = 0.f, cst3 = 0.f;
    float hn0 = 0.f, hn1 = 0.f, hn2 = 0.f, hn3 = 0.f;
    const floatx4 zac = {0.f, 0.f, 0.f, 0.f};

    const bool g0 = (grp == 0);
    const float* xrow = &s_seq[(pair * 16 + col) * 150];

#pragma unroll 1
    for (int t = 0; t < T_STEPS; t++) {
        float xv0 = xrow[t * 3 + 0];
        float xv1 = xrow[t * 3 + 1];
        float xv2 = xrow[t * 3 + 2];

        unsigned w0 = cvt_pk_bf16(xv0, xv1);
        unsigned w1 = cvt_pk_bf16(xv2, g0 ? 1.0f : 0.0f);
        float e0 = xv0 - lo16f(w0);
        float e1 = xv1 - hi16f(w0);
        float e2 = xv2 - lo16f(w1);
        unsigned w2 = g0 ? cvt_pk_bf16(e0, e1) : 0u;
        unsigned w3 = g0 ? cvt_pk_bf16(e2, 1.0f) : 0u;
        uint32x4 a2p = {w0, w1, w2, w3};
        short8 A2 = bc8(a2p);

        const float* hr = &s_h[pair][(t + 1) & 1][col][grp * 8];
        floatx4 h0 = *(const floatx4*)&hr[0];
        floatx4 h1 = *(const floatx4*)&hr[4];
        unsigned p0 = cvt_pk_bf16(h0[0], h0[1]);
        unsigned p1 = cvt_pk_bf16(h0[2], h0[3]);
        unsigned p2 = cvt_pk_bf16(h1[0], h1[1]);
        unsigned p3 = cvt_pk_bf16(h1[2], h1[3]);
        uint32x4 hip = {p0, p1, p2, p3};
        short8 Ahi = bc8(hip);
        unsigned q0 = cvt_pk_bf16(h0[0] - lo16f(p0), h0[1] - hi16f(p0));
        unsigned q1 = cvt_pk_bf16(h0[2] - lo16f(p1), h0[3] - hi16f(p1));
        unsigned q2 = cvt_pk_bf16(h1[0] - lo16f(p2), h1[1] - hi16f(p2));
        unsigned q3 = cvt_pk_bf16(h1[2] - lo16f(p3), h1[3] - hi16f(p3));
        uint32x4 lop = {q0, q1, q2, q3};
        short8 Alo = bc8(lop);

        floatx4 d0 = __builtin_amdgcn_mfma_f32_16x16x32_bf16(A2, bc8(B2_0), zac, 0, 0, 0);
        d0 = __builtin_amdgcn_mfma_f32_16x16x32_bf16(Alo, bc8(BH_0), d0, 0, 0, 0);
        d0 = __builtin_amdgcn_mfma_f32_16x16x32_bf16(Ahi, bc8(BL_0), d0, 0, 0, 0);
        d0 = __builtin_amdgcn_mfma_f32_16x16x32_bf16(Ahi, bc8(BH_0), d0, 0, 0, 0);
        floatx4 d1 = __builtin_amdgcn_mfma_f32_16x16x32_bf16(A2, bc8(B2_1), zac, 0, 0, 0);
        d1 = __builtin_amdgcn_mfma_f32_16x16x32_bf16(Alo, bc8(BH_1), d1, 0, 0, 0);
        d1 = __builtin_amdgcn_mfma_f32_16x16x32_bf16(Ahi, bc8(BL_1), d1, 0, 0, 0);
        d1 = __builtin_amdgcn_mfma_f32_16x16x32_bf16(Ahi, bc8(BH_1), d1, 0, 0, 0);
        floatx4 d2 = __builtin_amdgcn_mfma_f32_16x16x32_bf16(A2, bc8(B2_2), zac, 0, 0, 0);
        d2 = __builtin_amdgcn_mfma_f32_16x16x32_bf16(Alo, bc8(BH_2), d2, 0, 0, 0);
        d2 = __builtin_amdgcn_mfma_f32_16x16x32_bf16(Ahi, bc8(BL_2), d2, 0, 0, 0);
        d2 = __builtin_amdgcn_mfma_f32_16x16x32_bf16(Ahi, bc8(BH_2), d2, 0, 0, 0);
        floatx4 d3 = __builtin_amdgcn_mfma_f32_16x16x32_bf16(A2, bc8(B2_3), zac, 0, 0, 0);
        d3 = __builtin_amdgcn_mfma_f32_16x16x32_bf16(Alo, bc8(BH_3), d3, 0, 0, 0);
        d3 = __builtin_amdgcn_mfma_f32_16x16x32_bf16(Ahi, bc8(BL_3), d3, 0, 0, 0);
        d3 = __builtin_amdgcn_mfma_f32_16x16x32_bf16(Ahi, bc8(BH_3), d3, 0, 0, 0);

        {
            float ig, fg, gv, og;
            ig = sigf(d0[0]); fg = sigf(d1[0]); gv = tanhfast(d2[0]); og = sigf(d3[0]);
            cst0 = fg * cst0 + ig * gv; hn0 = og * tanhfast(cst0);
            ig = sigf(d0[1]); fg = sigf(d1[1]); gv = tanhfast(d2[1]); og = sigf(d3[1]);
            cst1 = fg * cst1 + ig * gv; hn1 = og * tanhfast(cst1);
            ig = sigf(d0[2]); fg = sigf(d1[2]); gv = tanhfast(d2[2]); og = sigf(d3[2]);
            cst2 = fg * cst2 + ig * gv; hn2 = og * tanhfast(cst2);
            ig = sigf(d0[3]); fg = sigf(d1[3]); gv = tanhfast(d2[3]); og = sigf(d3[3]);
            cst3 = fg * cst3 + ig * gv; hn3 = og * tanhfast(cst3);
        }

        float* hw = &s_h[pair][t & 1][4 * grp][sub * 16 + col];
        hw[0 * 36] = hn0; hw[1 * 36] = hn1; hw[2 * 36] = hn2; hw[3 * 36] = hn3;
        __syncthreads();
    }

    {
        int node = node0 + 4 * grp;
        const int c = sub * 16 + col;
        if (node + 0 < N) t_out[(size_t)(node + 0) * LSTM_H + c] = hn0;
        if (node + 1 < N) t_out[(size_t)(node + 1) * LSTM_H + c] = hn1;
        if (node + 2 < N) t_out[(size_t)(node + 2) * LSTM_H + c] = hn2;
        if (node + 3 < N) t_out[(size_t)(node + 3) * LSTM_H + c] = hn3;
    }
}

// ---------- fusion MLP ----------
__global__ void fusion_kernel(const float* __restrict__ g2, const float* __restrict__ tt,
                              const float* __restrict__ Wf1, const float* __restrict__ bf1,
                              const float* __restrict__ Wf2, const float* __restrict__ bf2,
                              float* __restrict__ out, int N) {
    __shared__ float sW[96 * 64];
    __shared__ float sb1[64];
    __shared__ float sW2[128];
    for (int i = threadIdx.x; i < 96 * 64; i += 256) sW[i] = Wf1[i];
    if (threadIdx.x < 64) sb1[threadIdx.x] = bf1[threadIdx.x];
    if (threadIdx.x < 128) sW2[threadIdx.x] = Wf2[threadIdx.x];
    __syncthreads();
    const int wave = threadIdx.x >> 6;
    const int lane = threadIdx.x & 63;
    for (int n = blockIdx.x * 4 + wave; n < N; n += gridDim.x * 4) {
        const float* gn = g2 + (size_t)n * 64;
        const float* tn = tt + (size_t)n * 32;
        float acc = sb1[lane];
#pragma unroll 8
        for (int k = 0; k < 64; k++) acc += gn[k] * sW[k * 64 + lane];
#pragma unroll 8
        for (int k = 0; k < 32; k++) acc += tn[k] * sW[(64 + k) * 64 + lane];
        acc = fmaxf(acc, 0.0f);
        float o0 = acc * sW2[lane * 2 + 0];
        float o1 = acc * sW2[lane * 2 + 1];
#pragma unroll
        for (int mk = 32; mk >= 1; mk >>= 1) {
            o0 += __shfl_xor(o0, mk);
            o1 += __shfl_xor(o1, mk);
        }
        if (lane == 0) {
            out[(size_t)n * 2 + 0] = o0 + bf2[0];
            out[(size_t)n * 2 + 1] = o1 + bf2[1];
        }
    }
}

extern "C" void kernel_launch(void* const* d_in, const int* in_sizes, int n_in,
                              void* d_out, int out_size, void* d_ws, size_t ws_size,
                              hipStream_t stream) {
    const float* x      = (const float*)d_in[0];
    const int*   eidx   = (const int*)d_in[1];
    const float* seq    = (const float*)d_in[2];
    const float* W1     = (const float*)d_in[3];
    const float* att_s1 = (const float*)d_in[4];
    const float* att_d1 = (const float*)d_in[5];
    const float* bias1  = (const float*)d_in[6];
    const float* W2     = (const float*)d_in[7];
    const float* att_s2 = (const float*)d_in[8];
    const float* att_d2 = (const float*)d_in[9];
    const float* bias2  = (const float*)d_in[10];
    const float* Wih    = (const float*)d_in[11];
    const float* Whh    = (const float*)d_in[12];
    const float* bih    = (const float*)d_in[13];
    const float* bhh    = (const float*)d_in[14];
    const float* Wf1    = (const float*)d_in[15];
    const float* bf1    = (const float*)d_in[16];
    const float* Wf2    = (const float*)d_in[17];
    const float* bf2    = (const float*)d_in[18];
    float* out = (float*)d_out;

    const int N  = in_sizes[0] / IN_F;   // 50000
    const int E  = in_sizes[1] / 2;      // 800000
    const int ET = E + N;
    const int* srcs = eidx;
    const int* dsts = eidx + E;

    // workspace layout
    float* fws = (float*)d_ws;
    size_t o = 0;
    float* h1  = fws + o; o += (size_t)N * 256;
    float* g1  = fws + o; o += (size_t)N * 256;
    float* as1 = fws + o; o += (size_t)N * 4;
    float* ad1 = fws + o; o += (size_t)N * 4;
    int* cnt    = (int*)(fws + o);
    int* rowp   = cnt + N;
    int* cursor = rowp + N + 1;
    int* eid    = cursor + N;
    int* bsum   = eid + ET;
    // prepacked LSTM weight fragments (24.5 KB, 16B-aligned)
    uintptr_t wp_ = (uintptr_t)(bsum + 512);
    wp_ = (wp_ + 15) & ~(uintptr_t)15;
    uint32x4* wsp = (uint32x4*)wp_;
    // prepacked transposed GEMM weights (hi/lo): W1t 2x32768, W2t 2x16384 shorts
    unsigned short* w1h = (unsigned short*)(wsp + 1536);
    unsigned short* w1l = w1h + 32768;
    unsigned short* w2h = w1l + 32768;
    unsigned short* w2l = w2h + 16384;
    // layer-2 / LSTM aliases (h1 region dead after layer-1 aggregation)
    float* h2 = h1;                      // N*64
    float* g2 = h1 + (size_t)N * 64;     // N*64
    float* tt = h1 + (size_t)N * 128;    // N*32
    float* as2 = as1; float* ad2 = ad1;

    const int nTiles = (N + 255) / 256;
    dim3 blk(256);

    // ---- CSR build ----
    hipMemsetAsync(cnt, 0, (size_t)N * sizeof(int), stream);
    hipMemsetAsync(cursor, 0, (size_t)N * sizeof(int), stream);
    count_deg<<<(ET + 255) / 256, blk, 0, stream>>>(dsts, E, ET, cnt);
    scan1<<<nTiles, blk, 0, stream>>>(cnt, rowp, bsum, N);
    scan2<<<1, blk, 0, stream>>>(bsum, nTiles);
    scan3<<<(N + 256) / 256, blk, 0, stream>>>(rowp, bsum, N, ET);
    scatter_edges<<<(ET + 255) / 256, blk, 0, stream>>>(dsts, E, ET, rowp, cursor, eid);

    // ---- weight prepacks (tiny, once) ----
    prep_wsplit<<<1, 512, 0, stream>>>(Wih, Whh, bih, bhh, wsp);
    prep_wt<128><<<(32768 + 255) / 256, blk, 0, stream>>>(W1, w1h, w1l, 32768, 256);
    prep_wt<256><<<(16384 + 255) / 256, blk, 0, stream>>>(W2, w2h, w2l, 16384, 64);

    // ---- GAT layer 1 (MFMA split-bf16 GEMM) ----
    gemm_mfma<128, 256><<<dim3((N + 127) / 128, 4), blk, 0, stream>>>(x, w1h, w1l, h1, N);
    att_scores<<<(N * 4 + 255) / 256, blk, 0, stream>>>(h1, att_s1, att_d1, as1, ad1, N * 4, 3);
    gat_agg4_sp<<<(N + 3) / 4, blk, 0, stream>>>(srcs, E, rowp, eid, as1, ad1, h1, bias1, g1, N);

    // ---- LSTM ----
    lstm_mfma<<<(N + 63) / 64, dim3(512), 0, stream>>>(seq, wsp, tt, N);

    // ---- GAT layer 2 (MFMA split-bf16 GEMM) ----
    gemm_mfma<256, 64><<<dim3((N + 127) / 128, 1), blk, 0, stream>>>(g1, w2h, w2l, h2, N);
    att_scores<<<(N + 255) / 256, blk, 0, stream>>>(h2, att_s2, att_d2, as2, ad2, N, 0);
    gat_agg1_sp<<<(N + 3) / 4, blk, 0, stream>>>(srcs, E, rowp, eid, as2, ad2, h2, bias2, g2, N);

    // ---- fusion MLP ----
    fusion_kernel<<<512, blk, 0, stream>>>(g2, tt, Wf1, bf1, Wf2, bf2, out, N);
}

// Round 10
// 726.689 us; speedup vs baseline: 1.2326x; 1.0065x over previous
//
#include <hip/hip_runtime.h>
#include <math.h>

#define HEADS1 4
#define HID 64
#define LSTM_H 32
#define IN_F 128
#define T_STEPS 50
#define NEG_SLOPE 0.2f
#define EPS_A 1e-16f

typedef __attribute__((ext_vector_type(8))) short short8;
typedef __attribute__((ext_vector_type(4))) float floatx4;
typedef __attribute__((ext_vector_type(4))) unsigned uint32x4;

// ---------- helpers ----------
// Single-instruction reciprocal (1 ulp). Without -ffast-math the compiler
// expands 1.0f/x to the ~12-inst IEEE div sequence. [r16: -42% on lstm]
__device__ __forceinline__ float frcp(float x) {
    float r;
    asm("v_rcp_f32 %0, %1" : "=v"(r) : "v"(x));
    return r;
}
__device__ __forceinline__ float sigf(float x) { return frcp(1.0f + __expf(-x)); }
__device__ __forceinline__ float tanhfast(float x) {
    float e = __expf(2.0f * x);
    return 1.0f - 2.0f * frcp(e + 1.0f);
}
__device__ __forceinline__ unsigned short f2bf(float f) {
    unsigned u = __float_as_uint(f);
    unsigned r = (u + 0x7FFFu + ((u >> 16) & 1u)) >> 16;
    return (unsigned short)r;
}
__device__ __forceinline__ float bf2f(unsigned short s) {
    return __uint_as_float(((unsigned)s) << 16);
}
// HW packed fp32->bf16 (2 values / instruction); no builtin on gfx950, inline asm.
__device__ __forceinline__ unsigned cvt_pk_bf16(float a, float b) {
    unsigned r;
    asm("v_cvt_pk_bf16_f32 %0, %1, %2" : "=v"(r) : "v"(a), "v"(b));
    return r;
}
__device__ __forceinline__ float lo16f(unsigned p) { return __uint_as_float(p << 16); }
__device__ __forceinline__ float hi16f(unsigned p) { return __uint_as_float(p & 0xffff0000u); }
__device__ __forceinline__ short8 bc8(uint32x4 v) { return __builtin_bit_cast(short8, v); }

// ---------- weight transpose+split prepack for MFMA GEMM ----------
template <int KK>
__global__ void prep_wt(const float* __restrict__ W, unsigned short* __restrict__ th,
                        unsigned short* __restrict__ tl, int total, int NC) {
    int i = blockIdx.x * 256 + threadIdx.x;
    if (i >= total) return;
    int n = i / KK, k = i - n * KK;
    float v = W[k * NC + n];
    unsigned short h = f2bf(v);
    th[i] = h;
    tl[i] = f2bf(v - bf2f(h));
}

// ---------- MFMA GEMM: C[M,NC] = A[M,K] @ B[K,NC], split-bf16 3-product ----
template <int K, int NC>
__global__ __launch_bounds__(256)
void gemm_mfma(const float* __restrict__ A, const unsigned short* __restrict__ Bth,
               const unsigned short* __restrict__ Btl, float* __restrict__ C, int M) {
    __shared__ float sA[128][44];            // 22.5 KB
    __shared__ unsigned short sBh[64][40];   // 5 KB
    __shared__ unsigned short sBl[64][40];   // 5 KB
    const int tid = threadIdx.x;
    const int wave = tid >> 6, lane = tid & 63;
    const int wr = wave >> 1, wc = wave & 1;
    const int row0 = blockIdx.x * 128;
    const int col0 = blockIdx.y * 64;
    const int l15 = lane & 15, l4 = lane >> 4;

    floatx4 acc[4][2];
#pragma unroll
    for (int rb = 0; rb < 4; rb++)
#pragma unroll
        for (int cb = 0; cb < 2; cb++) acc[rb][cb] = (floatx4){0.f, 0.f, 0.f, 0.f};

    for (int k0 = 0; k0 < K; k0 += 32) {
        __syncthreads();
#pragma unroll
        for (int q = 0; q < 4; q++) {
            int idx = q * 256 + tid;
            int row = idx >> 3, seg = idx & 7;
            int gr = row0 + row;
            float4 v = (gr < M) ? *(const float4*)&A[(size_t)gr * K + k0 + seg * 4]
                                : make_float4(0.f, 0.f, 0.f, 0.f);
            *(float4*)&sA[row][seg * 4] = v;
        }
        {
            int col = tid >> 2, seg = tid & 3;
            size_t gb = (size_t)(col0 + col) * K + k0 + seg * 8;
            *(short8*)&sBh[col][seg * 8] = *(const short8*)&Bth[gb];
            *(short8*)&sBl[col][seg * 8] = *(const short8*)&Btl[gb];
        }
        __syncthreads();

        short8 bh0 = *(const short8*)&sBh[wc * 32 + 0 + l15][l4 * 8];
        short8 bl0 = *(const short8*)&sBl[wc * 32 + 0 + l15][l4 * 8];
        short8 bh1 = *(const short8*)&sBh[wc * 32 + 16 + l15][l4 * 8];
        short8 bl1 = *(const short8*)&sBl[wc * 32 + 16 + l15][l4 * 8];

#pragma unroll
        for (int rb = 0; rb < 4; rb++) {
            int row = wr * 64 + rb * 16 + l15;
            floatx4 a0 = *(const floatx4*)&sA[row][l4 * 8 + 0];
            floatx4 a1 = *(const floatx4*)&sA[row][l4 * 8 + 4];
            unsigned p0 = cvt_pk_bf16(a0[0], a0[1]);
            unsigned p1 = cvt_pk_bf16(a0[2], a0[3]);
            unsigned p2 = cvt_pk_bf16(a1[0], a1[1]);
            unsigned p3 = cvt_pk_bf16(a1[2], a1[3]);
            uint32x4 hp = {p0, p1, p2, p3};
            short8 Ah = bc8(hp);
            unsigned q0 = cvt_pk_bf16(a0[0] - lo16f(p0), a0[1] - hi16f(p0));
            unsigned q1 = cvt_pk_bf16(a0[2] - lo16f(p1), a0[3] - hi16f(p1));
            unsigned q2 = cvt_pk_bf16(a1[0] - lo16f(p2), a1[1] - hi16f(p2));
            unsigned q3 = cvt_pk_bf16(a1[2] - lo16f(p3), a1[3] - hi16f(p3));
            uint32x4 lp = {q0, q1, q2, q3};
            short8 Al = bc8(lp);

            acc[rb][0] = __builtin_amdgcn_mfma_f32_16x16x32_bf16(Ah, bh0, acc[rb][0], 0, 0, 0);
            acc[rb][0] = __builtin_amdgcn_mfma_f32_16x16x32_bf16(Ah, bl0, acc[rb][0], 0, 0, 0);
            acc[rb][0] = __builtin_amdgcn_mfma_f32_16x16x32_bf16(Al, bh0, acc[rb][0], 0, 0, 0);
            acc[rb][1] = __builtin_amdgcn_mfma_f32_16x16x32_bf16(Ah, bh1, acc[rb][1], 0, 0, 0);
            acc[rb][1] = __builtin_amdgcn_mfma_f32_16x16x32_bf16(Ah, bl1, acc[rb][1], 0, 0, 0);
            acc[rb][1] = __builtin_amdgcn_mfma_f32_16x16x32_bf16(Al, bh1, acc[rb][1], 0, 0, 0);
        }
    }

#pragma unroll
    for (int rb = 0; rb < 4; rb++)
#pragma unroll
        for (int cb = 0; cb < 2; cb++)
#pragma unroll
            for (int q = 0; q < 4; q++) {
                int row = row0 + wr * 64 + rb * 16 + l4 * 4 + q;
                int col = col0 + wc * 32 + cb * 16 + l15;
                if (row < M) C[(size_t)row * NC + col] = acc[rb][cb][q];
            }
}

// ---------- attention scores ----------
__global__ void att_scores(const float* __restrict__ h, const float* __restrict__ att_s,
                           const float* __restrict__ att_d, float* __restrict__ as_,
                           float* __restrict__ ad_, int NH, int Hmask) {
    int i = blockIdx.x * blockDim.x + threadIdx.x;
    if (i >= NH) return;
    int hh = i & Hmask;
    const float* row = h + (size_t)i * HID;
    float s = 0.0f, d = 0.0f;
#pragma unroll 8
    for (int c = 0; c < HID; c++) {
        float v = row[c];
        s += v * att_s[hh * HID + c];
        d += v * att_d[hh * HID + c];
    }
    as_[i] = s;
    ad_[i] = d;
}

// ---------- CSR build ----------
__global__ void count_deg(const int* __restrict__ dsts, int E, int ET, int* __restrict__ cnt) {
    int e = blockIdx.x * blockDim.x + threadIdx.x;
    if (e >= ET) return;
    int d = (e < E) ? dsts[e] : (e - E);
    atomicAdd(&cnt[d], 1);
}

__global__ void scan1(const int* __restrict__ cnt, int* __restrict__ rowp,
                      int* __restrict__ bsum, int N) {
    __shared__ int tmp[256];
    int i = blockIdx.x * 256 + threadIdx.x;
    int v = (i < N) ? cnt[i] : 0;
    tmp[threadIdx.x] = v;
    __syncthreads();
    for (int off = 1; off < 256; off <<= 1) {
        int t = (threadIdx.x >= (unsigned)off) ? tmp[threadIdx.x - off] : 0;
        __syncthreads();
        tmp[threadIdx.x] += t;
        __syncthreads();
    }
    if (i < N) rowp[i] = tmp[threadIdx.x] - v;
    if (threadIdx.x == 255) bsum[blockIdx.x] = tmp[255];
}

__global__ void scan2(int* __restrict__ bsum, int nb) {
    __shared__ int tmp[256];
    int v = (threadIdx.x < (unsigned)nb) ? bsum[threadIdx.x] : 0;
    tmp[threadIdx.x] = v;
    __syncthreads();
    for (int off = 1; off < 256; off <<= 1) {
        int t = (threadIdx.x >= (unsigned)off) ? tmp[threadIdx.x - off] : 0;
        __syncthreads();
        tmp[threadIdx.x] += t;
        __syncthreads();
    }
    if (threadIdx.x < (unsigned)nb) bsum[threadIdx.x] = tmp[threadIdx.x] - v;
}

__global__ void scan3(int* __restrict__ rowp, const int* __restrict__ bsum, int N, int ET) {
    int i = blockIdx.x * 256 + threadIdx.x;
    if (i < N) rowp[i] += bsum[blockIdx.x];
    if (i == 0) rowp[N] = ET;
}

__global__ void scatter_edges(const int* __restrict__ dsts, int E, int ET,
                              const int* __restrict__ rowp, int* __restrict__ cursor,
                              int* __restrict__ eid) {
    int e = blockIdx.x * blockDim.x + threadIdx.x;
    if (e >= ET) return;
    int d = (e < E) ? dsts[e] : (e - E);
    int pos = atomicAdd(&cursor[d], 1);
    eid[rowp[d] + pos] = e;
}

// ---------- GAT layer-1 aggregation: single pass, one wave per dst, 4 heads ----------
__global__ __launch_bounds__(256)
void gat_agg4_sp(const int* __restrict__ srcs, int E,
                 const int* __restrict__ rowp, const int* __restrict__ eid,
                 const float* __restrict__ as_, const float* __restrict__ ad_,
                 const float* __restrict__ hfeat, const float* __restrict__ bias,
                 float* __restrict__ g, int N) {
    __shared__ float s_alpha[4][64][4];
    const int wave = threadIdx.x >> 6;
    const int lane = threadIdx.x & 63;
    const int head = lane >> 4;
    const int dst = blockIdx.x * 4 + wave;
    if (dst >= N) return;
    const int start = rowp[dst], end = rowp[dst + 1];
    const float4 adv = ((const float4*)ad_)[dst];
    const float4* h4 = (const float4*)hfeat;

    float4 dsum = make_float4(0.f, 0.f, 0.f, 0.f);
    float4 acc  = make_float4(0.f, 0.f, 0.f, 0.f);

    for (int i0 = start; i0 < end; i0 += 64) {
        int cnt = min(64, end - i0);
        int i = i0 + lane;
        int s = 0;
        if (i < end) {
            int e = eid[i];
            s = (e < E) ? srcs[e] : (e - E);
            float4 a = ((const float4*)as_)[s];
            float tx, ex;
            tx = a.x + adv.x; tx = (tx > 0.f) ? tx : NEG_SLOPE * tx; ex = __expf(tx);
            dsum.x += ex; s_alpha[wave][lane][0] = ex;
            tx = a.y + adv.y; tx = (tx > 0.f) ? tx : NEG_SLOPE * tx; ex = __expf(tx);
            dsum.y += ex; s_alpha[wave][lane][1] = ex;
            tx = a.z + adv.z; tx = (tx > 0.f) ? tx : NEG_SLOPE * tx; ex = __expf(tx);
            dsum.z += ex; s_alpha[wave][lane][2] = ex;
            tx = a.w + adv.w; tx = (tx > 0.f) ? tx : NEG_SLOPE * tx; ex = __expf(tx);
            dsum.w += ex; s_alpha[wave][lane][3] = ex;
        }
        __builtin_amdgcn_wave_barrier();
#pragma unroll 4
        for (int k = 0; k < cnt; k++) {
            float a_k = s_alpha[wave][k][head];   // 16-lane broadcast read
            int   s_k = __shfl(s, k);
            float4 hv = h4[(size_t)s_k * 64 + lane];
            acc.x += a_k * hv.x; acc.y += a_k * hv.y;
            acc.z += a_k * hv.z; acc.w += a_k * hv.w;
        }
        __builtin_amdgcn_wave_barrier();
    }
#pragma unroll
    for (int mk = 32; mk >= 1; mk >>= 1) {
        dsum.x += __shfl_xor(dsum.x, mk);
        dsum.y += __shfl_xor(dsum.y, mk);
        dsum.z += __shfl_xor(dsum.z, mk);
        dsum.w += __shfl_xor(dsum.w, mk);
    }
    float den = (head == 0) ? dsum.x : (head == 1) ? dsum.y : (head == 2) ? dsum.z : dsum.w;
    float inv = 1.0f / (den + EPS_A);
    float4 b4 = ((const float4*)bias)[lane];
    float4 r;
    r.x = acc.x * inv + b4.x; r.x = (r.x > 0.f) ? r.x : __expf(r.x) - 1.f;
    r.y = acc.y * inv + b4.y; r.y = (r.y > 0.f) ? r.y : __expf(r.y) - 1.f;
    r.z = acc.z * inv + b4.z; r.z = (r.z > 0.f) ? r.z : __expf(r.z) - 1.f;
    r.w = acc.w * inv + b4.w; r.w = (r.w > 0.f) ? r.w : __expf(r.w) - 1.f;
    ((float4*)g)[(size_t)dst * 64 + lane] = r;
}

// ---------- GAT layer-2 aggregation: single pass, one wave per dst, H=1 ----------
__global__ __launch_bounds__(256)
void gat_agg1_sp(const int* __restrict__ srcs, int E,
                 const int* __restrict__ rowp, const int* __restrict__ eid,
                 const float* __restrict__ as_, const float* __restrict__ ad_,
                 const float* __restrict__ hfeat, const float* __restrict__ bias,
                 float* __restrict__ g, int N) {
    __shared__ float s_alpha[4][64];
    const int wave = threadIdx.x >> 6;
    const int lane = threadIdx.x & 63;
    const int dst = blockIdx.x * 4 + wave;
    if (dst >= N) return;
    const int start = rowp[dst], end = rowp[dst + 1];
    const float adv = ad_[dst];

    float dsum = 0.0f, acc = 0.0f;
    for (int i0 = start; i0 < end; i0 += 64) {
        int cnt = min(64, end - i0);
        int i = i0 + lane;
        int s = 0;
        if (i < end) {
            int e = eid[i];
            s = (e < E) ? srcs[e] : (e - E);
            float t = as_[s] + adv;
            t = (t > 0.f) ? t : NEG_SLOPE * t;
            float ex = __expf(t);
            dsum += ex;
            s_alpha[wave][lane] = ex;
        }
        __builtin_amdgcn_wave_barrier();
#pragma unroll 4
        for (int k = 0; k < cnt; k++) {
            float a_k = s_alpha[wave][k];         // full-wave broadcast read
            int   s_k = __shfl(s, k);
            acc += a_k * hfeat[(size_t)s_k * 64 + lane];
        }
        __builtin_amdgcn_wave_barrier();
    }
#pragma unroll
    for (int mk = 32; mk >= 1; mk >>= 1) dsum += __shfl_xor(dsum, mk);
    g[(size_t)dst * 64 + lane] = acc / (dsum + EPS_A) + bias[lane];
}

// ---------- LSTM weight prepack (runs once, 1 block) ----------
__global__ void prep_wsplit(const float* __restrict__ Wih, const float* __restrict__ Whh,
                            const float* __restrict__ bih, const float* __restrict__ bhh,
                            uint32x4* __restrict__ wsp) {
    const int tid = threadIdx.x;          // 0..511
    const int kk = tid >> 7, sub = (tid >> 6) & 1, lane = tid & 63;
    const int grp = lane >> 4, col = lane & 15;
    const int krow = grp * 8;
    const int n = (sub + kk * 2) * 16 + col;
    float w[8];
    *(float4*)&w[0] = *(const float4*)&Whh[n * 32 + krow + 0];
    *(float4*)&w[4] = *(const float4*)&Whh[n * 32 + krow + 4];
    unsigned hi[8], lo[8];
#pragma unroll
    for (int j = 0; j < 8; j++) {
        unsigned short hs = f2bf(w[j]);
        hi[j] = hs;
        lo[j] = f2bf(w[j] - bf2f(hs));
    }
    uint32x4 BH = {hi[0] | (hi[1] << 16), hi[2] | (hi[3] << 16),
                   hi[4] | (hi[5] << 16), hi[6] | (hi[7] << 16)};
    uint32x4 BL = {lo[0] | (lo[1] << 16), lo[2] | (lo[3] << 16),
                   lo[4] | (lo[5] << 16), lo[6] | (lo[7] << 16)};
    float wi0 = Wih[n * 3 + 0], wi1 = Wih[n * 3 + 1], wi2 = Wih[n * 3 + 2];
    float bb = bih[n] + bhh[n];
    unsigned h0 = f2bf(wi0), h1 = f2bf(wi1), h2 = f2bf(wi2), hb = f2bf(bb);
    uint32x4 B2 = {0u, 0u, 0u, 0u};
    if (grp == 0) {
        unsigned bl_ = f2bf(bb - bf2f((unsigned short)hb));
        B2[0] = h0 | (h1 << 16); B2[1] = h2 | (hb << 16);
        B2[2] = h0 | (h1 << 16); B2[3] = h2 | (bl_ << 16);
    } else if (grp == 1) {
        unsigned l0 = f2bf(wi0 - bf2f((unsigned short)h0));
        unsigned l1 = f2bf(wi1 - bf2f((unsigned short)h1));
        unsigned l2 = f2bf(wi2 - bf2f((unsigned short)h2));
        B2[0] = l0 | (l1 << 16); B2[1] = l2;
    }
    wsp[((kk * 3 + 0) * 2 + sub) * 64 + lane] = B2;
    wsp[((kk * 3 + 1) * 2 + sub) * 64 + lane] = BH;
    wsp[((kk * 3 + 2) * 2 + sub) * 64 + lane] = BL;
}

// ---------- LSTM via MFMA (split-bf16), round-18 ----------
// Delta vs round 17: s_seq slab REMOVED (back to r12-style per-ts global x
// with one-step prefetch -- r13 A/B proved the slab is perf-neutral: 332us
// with vs 336us without). The slab was pure occupancy poison: LDS 56.8 ->
// 18.4 KB lifts residency 2 -> 4 blocks/CU (wave-capped at 32/CU), waves/SIMD
// 4 -> 8, and the 782-block grid becomes single-pass resident. r17 counters
// (VALUBusy 57%, Occupancy 30%) say the kernel has 43% idle issue slots =
// unhidden latency -- exactly what doubled TLP fills. waves_per_eu cap
// removed (would clamp at 4 waves/EU).
// VERIFY: LDS_Block_Size 18432, Occupancy ~55-65, dur ~125-150us.
__global__ __launch_bounds__(512)
void lstm_mfma(const float* __restrict__ seq, const uint32x4* __restrict__ wsp,
               float* __restrict__ t_out, int N) {
    __shared__ float s_h[4][2][16][36];     // [pair][pingpong][node][unit+pad] 18.4 KB

    const int tid  = threadIdx.x;
    const int wave = tid >> 6, lane = tid & 63;
    const int pair = wave >> 1, sub = wave & 1;
    const int grp  = lane >> 4, col = lane & 15;
    const int node0 = blockIdx.x * 64 + pair * 16;

    // ---- weight fragments: 12 coalesced 16B loads, no arithmetic ----
#define LF(KK, W) wsp[(((KK) * 3 + (W)) * 2 + sub) * 64 + lane]
    uint32x4 B2_0 = LF(0, 0), BH_0 = LF(0, 1), BL_0 = LF(0, 2);
    uint32x4 B2_1 = LF(1, 0), BH_1 = LF(1, 1), BL_1 = LF(1, 2);
    uint32x4 B2_2 = LF(2, 0), BH_2 = LF(2, 1), BL_2 = LF(2, 2);
    uint32x4 B2_3 = LF(3, 0), BH_3 = LF(3, 1), BL_3 = LF(3, 2);
#undef LF
    asm volatile("" : "+v"(B2_0), "+v"(BH_0), "+v"(BL_0),
                      "+v"(B2_1), "+v"(BH_1), "+v"(BL_1),
                      "+v"(B2_2), "+v"(BH_2), "+v"(BL_2),
                      "+v"(B2_3), "+v"(BH_3), "+v"(BL_3));

    for (int i = tid; i < 4 * 2 * 16 * 36; i += 512) ((float*)s_h)[i] = 0.0f;
    __syncthreads();

    float cst0 = 0.f, cst1 = 0.f, cst2 = 0.f, cst3 = 0.f;
    float hn0 = 0.f, hn1 = 0.f, hn2 = 0.f, hn3 = 0.f;
    const floatx4 zac = {0.f, 0.f, 0.f, 0.f};

    const int nodeX = node0 + col;
    const bool vx = (nodeX < N) && (grp < 2);
    const bool g0 = (grp == 0);
    const float* xp = seq + (size_t)nodeX * (T_STEPS * 3);

    // x for t=0
    float xv0 = vx ? xp[0] : 0.0f;
    float xv1 = vx ? xp[1] : 0.0f;
    float xv2 = vx ? xp[2] : 0.0f;

#pragma unroll 1
    for (int t = 0; t < T_STEPS; t++) {
        // ---- A2: x hi/lo + ones in K-slots (grp0: k'0-7, grp1: k'8-10) ----
        unsigned w0 = cvt_pk_bf16(xv0, xv1);
        unsigned w1 = cvt_pk_bf16(xv2, g0 ? 1.0f : 0.0f);
        float e0 = xv0 - lo16f(w0);
        float e1 = xv1 - hi16f(w0);
        float e2 = xv2 - lo16f(w1);
        unsigned w2 = g0 ? cvt_pk_bf16(e0, e1) : 0u;
        unsigned w3 = g0 ? cvt_pk_bf16(e2, 1.0f) : 0u;
        uint32x4 a2p = {w0, w1, w2, w3};
        short8 A2 = bc8(a2p);

        // ---- A (h) hi/lo from ping-pong LDS (prev buffer; t=0 reads zeros) ----
        const float* hr = &s_h[pair][(t + 1) & 1][col][grp * 8];
        floatx4 h0 = *(const floatx4*)&hr[0];
        floatx4 h1 = *(const floatx4*)&hr[4];
        unsigned p0 = cvt_pk_bf16(h0[0], h0[1]);
        unsigned p1 = cvt_pk_bf16(h0[2], h0[3]);
        unsigned p2 = cvt_pk_bf16(h1[0], h1[1]);
        unsigned p3 = cvt_pk_bf16(h1[2], h1[3]);
        uint32x4 hip = {p0, p1, p2, p3};
        short8 Ahi = bc8(hip);
        unsigned q0 = cvt_pk_bf16(h0[0] - lo16f(p0), h0[1] - hi16f(p0));
        unsigned q1 = cvt_pk_bf16(h0[2] - lo16f(p1), h0[3] - hi16f(p1));
        unsigned q2 = cvt_pk_bf16(h1[0] - lo16f(p2), h1[1] - hi16f(p2));
        unsigned q3 = cvt_pk_bf16(h1[2] - lo16f(p3), h1[3] - hi16f(p3));
        uint32x4 lop = {q0, q1, q2, q3};
        short8 Alo = bc8(lop);

        // ---- prefetch next x (clamped offset; hidden under MFMAs+gates) ----
        {
            int tn = (t + 1 < T_STEPS) ? (t + 1) : t;
            xv0 = vx ? xp[tn * 3 + 0] : 0.0f;
            xv1 = vx ? xp[tn * 3 + 1] : 0.0f;
            xv2 = vx ? xp[tn * 3 + 2] : 0.0f;
        }

        // ---- 4 gate-blocks x 4 MFMAs; all operands in registers ----
        floatx4 d0 = __builtin_amdgcn_mfma_f32_16x16x32_bf16(A2, bc8(B2_0), zac, 0, 0, 0);
        d0 = __builtin_amdgcn_mfma_f32_16x16x32_bf16(Alo, bc8(BH_0), d0, 0, 0, 0);
        d0 = __builtin_amdgcn_mfma_f32_16x16x32_bf16(Ahi, bc8(BL_0), d0, 0, 0, 0);
        d0 = __builtin_amdgcn_mfma_f32_16x16x32_bf16(Ahi, bc8(BH_0), d0, 0, 0, 0);
        floatx4 d1 = __builtin_amdgcn_mfma_f32_16x16x32_bf16(A2, bc8(B2_1), zac, 0, 0, 0);
        d1 = __builtin_amdgcn_mfma_f32_16x16x32_bf16(Alo, bc8(BH_1), d1, 0, 0, 0);
        d1 = __builtin_amdgcn_mfma_f32_16x16x32_bf16(Ahi, bc8(BL_1), d1, 0, 0, 0);
        d1 = __builtin_amdgcn_mfma_f32_16x16x32_bf16(Ahi, bc8(BH_1), d1, 0, 0, 0);
        floatx4 d2 = __builtin_amdgcn_mfma_f32_16x16x32_bf16(A2, bc8(B2_2), zac, 0, 0, 0);
        d2 = __builtin_amdgcn_mfma_f32_16x16x32_bf16(Alo, bc8(BH_2), d2, 0, 0, 0);
        d2 = __builtin_amdgcn_mfma_f32_16x16x32_bf16(Ahi, bc8(BL_2), d2, 0, 0, 0);
        d2 = __builtin_amdgcn_mfma_f32_16x16x32_bf16(Ahi, bc8(BH_2), d2, 0, 0, 0);
        floatx4 d3 = __builtin_amdgcn_mfma_f32_16x16x32_bf16(A2, bc8(B2_3), zac, 0, 0, 0);
        d3 = __builtin_amdgcn_mfma_f32_16x16x32_bf16(Alo, bc8(BH_3), d3, 0, 0, 0);
        d3 = __builtin_amdgcn_mfma_f32_16x16x32_bf16(Ahi, bc8(BL_3), d3, 0, 0, 0);
        d3 = __builtin_amdgcn_mfma_f32_16x16x32_bf16(Ahi, bc8(BH_3), d3, 0, 0, 0);

        // ---- gates: d0=i, d1=f, d2=g, d3=o; per-q unrolled, named state ----
        {
            float ig, fg, gv, og;
            ig = sigf(d0[0]); fg = sigf(d1[0]); gv = tanhfast(d2[0]); og = sigf(d3[0]);
            cst0 = fg * cst0 + ig * gv; hn0 = og * tanhfast(cst0);
            ig = sigf(d0[1]); fg = sigf(d1[1]); gv = tanhfast(d2[1]); og = sigf(d3[1]);
            cst1 = fg * cst1 + ig * gv; hn1 = og * tanhfast(cst1);
            ig = sigf(d0[2]); fg = sigf(d1[2]); gv = tanhfast(d2[2]); og = sigf(d3[2]);
            cst2 = fg * cst2 + ig * gv; hn2 = og * tanhfast(cst2);
            ig = sigf(d0[3]); fg = sigf(d1[3]); gv = tanhfast(d2[3]); og = sigf(d3[3]);
            cst3 = fg * cst3 + ig * gv; hn3 = og * tanhfast(cst3);
        }

        // ---- h writeback to ping-pong buffer, then pair-visible barrier ----
        float* hw = &s_h[pair][t & 1][4 * grp][sub * 16 + col];
        hw[0 * 36] = hn0; hw[1 * 36] = hn1; hw[2 * 36] = hn2; hw[3 * 36] = hn3;
        __syncthreads();
    }

    {
        int node = node0 + 4 * grp;
        const int c = sub * 16 + col;
        if (node + 0 < N) t_out[(size_t)(node + 0) * LSTM_H + c] = hn0;
        if (node + 1 < N) t_out[(size_t)(node + 1) * LSTM_H + c] = hn1;
        if (node + 2 < N) t_out[(size_t)(node + 2) * LSTM_H + c] = hn2;
        if (node + 3 < N) t_out[(size_t)(node + 3) * LSTM_H + c] = hn3;
    }
}

// ---------- fusion MLP ----------
__global__ void fusion_kernel(const float* __restrict__ g2, const float* __restrict__ tt,
                              const float* __restrict__ Wf1, const float* __restrict__ bf1,
                              const float* __restrict__ Wf2, const float* __restrict__ bf2,
                              float* __restrict__ out, int N) {
    __shared__ float sW[96 * 64];
    __shared__ float sb1[64];
    __shared__ float sW2[128];
    for (int i = threadIdx.x; i < 96 * 64; i += 256) sW[i] = Wf1[i];
    if (threadIdx.x < 64) sb1[threadIdx.x] = bf1[threadIdx.x];
    if (threadIdx.x < 128) sW2[threadIdx.x] = Wf2[threadIdx.x];
    __syncthreads();
    const int wave = threadIdx.x >> 6;
    const int lane = threadIdx.x & 63;
    for (int n = blockIdx.x * 4 + wave; n < N; n += gridDim.x * 4) {
        const float* gn = g2 + (size_t)n * 64;
        const float* tn = tt + (size_t)n * 32;
        float acc = sb1[lane];
#pragma unroll 8
        for (int k = 0; k < 64; k++) acc += gn[k] * sW[k * 64 + lane];
#pragma unroll 8
        for (int k = 0; k < 32; k++) acc += tn[k] * sW[(64 + k) * 64 + lane];
        acc = fmaxf(acc, 0.0f);
        float o0 = acc * sW2[lane * 2 + 0];
        float o1 = acc * sW2[lane * 2 + 1];
#pragma unroll
        for (int mk = 32; mk >= 1; mk >>= 1) {
            o0 += __shfl_xor(o0, mk);
            o1 += __shfl_xor(o1, mk);
        }
        if (lane == 0) {
            out[(size_t)n * 2 + 0] = o0 + bf2[0];
            out[(size_t)n * 2 + 1] = o1 + bf2[1];
        }
    }
}

extern "C" void kernel_launch(void* const* d_in, const int* in_sizes, int n_in,
                              void* d_out, int out_size, void* d_ws, size_t ws_size,
                              hipStream_t stream) {
    const float* x      = (const float*)d_in[0];
    const int*   eidx   = (const int*)d_in[1];
    const float* seq    = (const float*)d_in[2];
    const float* W1     = (const float*)d_in[3];
    const float* att_s1 = (const float*)d_in[4];
    const float* att_d1 = (const float*)d_in[5];
    const float* bias1  = (const float*)d_in[6];
    const float* W2     = (const float*)d_in[7];
    const float* att_s2 = (const float*)d_in[8];
    const float* att_d2 = (const float*)d_in[9];
    const float* bias2  = (const float*)d_in[10];
    const float* Wih    = (const float*)d_in[11];
    const float* Whh    = (const float*)d_in[12];
    const float* bih    = (const float*)d_in[13];
    const float* bhh    = (const float*)d_in[14];
    const float* Wf1    = (const float*)d_in[15];
    const float* bf1    = (const float*)d_in[16];
    const float* Wf2    = (const float*)d_in[17];
    const float* bf2    = (const float*)d_in[18];
    float* out = (float*)d_out;

    const int N  = in_sizes[0] / IN_F;   // 50000
    const int E  = in_sizes[1] / 2;      // 800000
    const int ET = E + N;
    const int* srcs = eidx;
    const int* dsts = eidx + E;

    // workspace layout
    float* fws = (float*)d_ws;
    size_t o = 0;
    float* h1  = fws + o; o += (size_t)N * 256;
    float* g1  = fws + o; o += (size_t)N * 256;
    float* as1 = fws + o; o += (size_t)N * 4;
    float* ad1 = fws + o; o += (size_t)N * 4;
    int* cnt    = (int*)(fws + o);
    int* rowp   = cnt + N;
    int* cursor = rowp + N + 1;
    int* eid    = cursor + N;
    int* bsum   = eid + ET;
    // prepacked LSTM weight fragments (24.5 KB, 16B-aligned)
    uintptr_t wp_ = (uintptr_t)(bsum + 512);
    wp_ = (wp_ + 15) & ~(uintptr_t)15;
    uint32x4* wsp = (uint32x4*)wp_;
    // prepacked transposed GEMM weights (hi/lo): W1t 2x32768, W2t 2x16384 shorts
    unsigned short* w1h = (unsigned short*)(wsp + 1536);
    unsigned short* w1l = w1h + 32768;
    unsigned short* w2h = w1l + 32768;
    unsigned short* w2l = w2h + 16384;
    // layer-2 / LSTM aliases (h1 region dead after layer-1 aggregation)
    float* h2 = h1;                      // N*64
    float* g2 = h1 + (size_t)N * 64;     // N*64
    float* tt = h1 + (size_t)N * 128;    // N*32
    float* as2 = as1; float* ad2 = ad1;

    const int nTiles = (N + 255) / 256;
    dim3 blk(256);

    // ---- CSR build ----
    hipMemsetAsync(cnt, 0, (size_t)N * sizeof(int), stream);
    hipMemsetAsync(cursor, 0, (size_t)N * sizeof(int), stream);
    count_deg<<<(ET + 255) / 256, blk, 0, stream>>>(dsts, E, ET, cnt);
    scan1<<<nTiles, blk, 0, stream>>>(cnt, rowp, bsum, N);
    scan2<<<1, blk, 0, stream>>>(bsum, nTiles);
    scan3<<<(N + 256) / 256, blk, 0, stream>>>(rowp, bsum, N, ET);
    scatter_edges<<<(ET + 255) / 256, blk, 0, stream>>>(dsts, E, ET, rowp, cursor, eid);

    // ---- weight prepacks (tiny, once) ----
    prep_wsplit<<<1, 512, 0, stream>>>(Wih, Whh, bih, bhh, wsp);
    prep_wt<128><<<(32768 + 255) / 256, blk, 0, stream>>>(W1, w1h, w1l, 32768, 256);
    prep_wt<256><<<(16384 + 255) / 256, blk, 0, stream>>>(W2, w2h, w2l, 16384, 64);

    // ---- GAT layer 1 (MFMA split-bf16 GEMM) ----
    gemm_mfma<128, 256><<<dim3((N + 127) / 128, 4), blk, 0, stream>>>(x, w1h, w1l, h1, N);
    att_scores<<<(N * 4 + 255) / 256, blk, 0, stream>>>(h1, att_s1, att_d1, as1, ad1, N * 4, 3);
    gat_agg4_sp<<<(N + 3) / 4, blk, 0, stream>>>(srcs, E, rowp, eid, as1, ad1, h1, bias1, g1, N);

    // ---- LSTM (MFMA; 18.4 KB LDS -> 4 blocks/CU, single-pass grid) ----
    lstm_mfma<<<(N + 63) / 64, dim3(512), 0, stream>>>(seq, wsp, tt, N);

    // ---- GAT layer 2 (MFMA split-bf16 GEMM) ----
    gemm_mfma<256, 64><<<dim3((N + 127) / 128, 1), blk, 0, stream>>>(g1, w2h, w2l, h2, N);
    att_scores<<<(N + 255) / 256, blk, 0, stream>>>(h2, att_s2, att_d2, as2, ad2, N, 0);
    gat_agg1_sp<<<(N + 3) / 4, blk, 0, stream>>>(srcs, E, rowp, eid, as2, ad2, h2, bias2, g2, N);

    // ---- fusion MLP ----
    fusion_kernel<<<512, blk, 0, stream>>>(g2, tt, Wf1, bf1, Wf2, bf2, out, N);
}